// Round 1
// baseline (1588.848 us; speedup 1.0000x reference)
//
#include <hip/hip_runtime.h>
#include <math.h>

#define SEQ  2048
#define DM   1024
#define NH   16
#define DK   64
#define MTOT 4096   // BATCH * SEQ
#define BATCH 2

// =====================================================================
// Projection GEMM: C[m][n] = sum_k X[m][k] * W[n][k]   (einsum bsi,oi->bso)
// M=4096, N=1024, K=1024. Tile 64x64, BK=16, 256 threads, 4x4 microtile.
// MODE 0: plain row-major store to out0 (final projection).
// MODE 1: blockIdx.z selects {Wq,Wk,Wv}; RoPE applied for mats 0,1;
//         scatter-store into (b, h, s, d) layout.
// =====================================================================
template <int MODE>
__global__ __launch_bounds__(256) void proj_kernel(
    const float* __restrict__ X, const float* __restrict__ W0,
    const float* __restrict__ W1, const float* __restrict__ W2,
    const int* __restrict__ pos, float* __restrict__ out0,
    float* __restrict__ out1, float* __restrict__ out2)
{
    const int t  = threadIdx.x;
    const int bn = blockIdx.x;              // 16 N-tiles (== head index)
    const int bm = blockIdx.y;              // 64 M-tiles
    const int mat = (MODE == 1) ? blockIdx.z : 0;

    const float* __restrict__ W =
        (MODE == 1) ? (mat == 0 ? W0 : (mat == 1 ? W1 : W2)) : W0;
    float* __restrict__ out =
        (MODE == 1) ? (mat == 0 ? out0 : (mat == 1 ? out1 : out2)) : out0;

    // k-major LDS tiles: As[k][m], Bs[k][n]; stride 68 floats (16B-aligned rows)
    __shared__ float As[16][68];
    __shared__ float Bs[16][68];

    const int lrow = t >> 2;                // 0..63 (tile row to load)
    const int lk4  = (t & 3) * 4;           // 0,4,8,12
    const int tx   = t & 15, ty = t >> 4;   // 16x16 thread grid

    const float* aptr = X + (bm * 64 + lrow) * DM + lk4;
    const float* bptr = W + (bn * 64 + lrow) * DM + lk4;

    float acc[4][4] = {};

    for (int kt = 0; kt < DM; kt += 16) {
        float4 av = *(const float4*)(aptr + kt);
        float4 bv = *(const float4*)(bptr + kt);
        __syncthreads();
        As[lk4 + 0][lrow] = av.x;
        As[lk4 + 1][lrow] = av.y;
        As[lk4 + 2][lrow] = av.z;
        As[lk4 + 3][lrow] = av.w;
        Bs[lk4 + 0][lrow] = bv.x;
        Bs[lk4 + 1][lrow] = bv.y;
        Bs[lk4 + 2][lrow] = bv.z;
        Bs[lk4 + 3][lrow] = bv.w;
        __syncthreads();
#pragma unroll
        for (int kk = 0; kk < 16; ++kk) {
            float4 a4 = *(const float4*)&As[kk][ty * 4];
            float4 b4 = *(const float4*)&Bs[kk][tx * 4];
            float a[4] = {a4.x, a4.y, a4.z, a4.w};
            float b[4] = {b4.x, b4.y, b4.z, b4.w};
#pragma unroll
            for (int i = 0; i < 4; ++i)
#pragma unroll
                for (int j = 0; j < 4; ++j) acc[i][j] += a[i] * b[j];
        }
    }

    const int m0 = bm * 64 + ty * 4;
    const int n0 = bn * 64 + tx * 4;   // head h == bn, d = tx*4 + j

    if (MODE == 0) {
#pragma unroll
        for (int i = 0; i < 4; ++i) {
            float4 v = make_float4(acc[i][0], acc[i][1], acc[i][2], acc[i][3]);
            *(float4*)&out[(m0 + i) * DM + n0] = v;
        }
    } else {
        const int h = bn;
        const int d0 = tx * 4;
#pragma unroll
        for (int i = 0; i < 4; ++i) {
            const int m = m0 + i;
            const int b = m >> 11;           // / SEQ
            const int sidx = m & 2047;       // % SEQ
            float* dst = out + (((b * NH + h) * SEQ + sidx) * DK) + d0;
            if (mat == 2) {
                *(float4*)dst = make_float4(acc[i][0], acc[i][1], acc[i][2], acc[i][3]);
            } else {
                const float pf = (float)pos[sidx];
                float vals[4];
#pragma unroll
                for (int jp = 0; jp < 2; ++jp) {
                    const int dpair = d0 + 2 * jp;   // even d in [0,64)
                    // inv_freq = 10000^(-dpair/64) = exp(-dpair/64 * ln(10000))
                    const float freq = expf(-(float)dpair * (9.210340371976184f / 64.0f));
                    const float ang = pf * freq;
                    float sn, cs;
                    sincosf(ang, &sn, &cs);
                    const float e  = acc[i][2 * jp];
                    const float od = acc[i][2 * jp + 1];
                    vals[2 * jp]     = e * cs - od * sn;
                    vals[2 * jp + 1] = e * sn + od * cs;
                }
                *(float4*)dst = make_float4(vals[0], vals[1], vals[2], vals[3]);
            }
        }
    }
}

// =====================================================================
// Causal flash attention, fp32. Q-tile 32 rows, K-tile 64 keys.
// 256 threads: 8 threads per Q-row (r = t>>3), each owns 8 cols (cg = t&7).
// Q/K/V in (b, h, s, d) layout; output scattered to (b, s, h*64+d).
// =====================================================================
#define QT 32
#define KT 64

__global__ __launch_bounds__(256) void attn_kernel(
    const float* __restrict__ Qb, const float* __restrict__ Kb,
    const float* __restrict__ Vb, float* __restrict__ Ob)
{
    const int t  = threadIdx.x;
    const int qt = blockIdx.x;   // 0..63
    const int h  = blockIdx.y;   // 0..15
    const int b  = blockIdx.z;   // 0..1

    const float* Qh = Qb + ((b * NH + h) * SEQ) * DK;
    const float* Kh = Kb + ((b * NH + h) * SEQ) * DK;
    const float* Vh = Vb + ((b * NH + h) * SEQ) * DK;

    __shared__ float Qs[QT][68];
    __shared__ float Ks[KT][68];
    __shared__ float Vs[KT][68];
    __shared__ float Ps[QT][68];

    const int r  = t >> 3;   // 0..31
    const int cg = t & 7;    // 0..7

    // Load Q tile: 32x64 floats = 512 float4, 2 per thread.
#pragma unroll
    for (int i = 0; i < 2; ++i) {
        const int f = t + i * 256;
        const int row = f >> 4;
        const int c4 = (f & 15) * 4;
        *(float4*)&Qs[row][c4] = *(const float4*)(Qh + (qt * QT + row) * DK + c4);
    }

    float m_i = -1e30f, l_i = 0.f;
    float acc[8] = {};

    const int qg0 = qt * QT;
    const int qg = qg0 + r;
    const int ktmax = (qg0 + QT - 1) >> 6;

    for (int kt = 0; kt <= ktmax; ++kt) {
        __syncthreads();   // previous iteration's Ps/Vs reads done (and Q load)
#pragma unroll
        for (int i = 0; i < 4; ++i) {
            const int f = t + i * 256;
            const int row = f >> 4;
            const int c4 = (f & 15) * 4;
            *(float4*)&Ks[row][c4] = *(const float4*)(Kh + (kt * KT + row) * DK + c4);
            *(float4*)&Vs[row][c4] = *(const float4*)(Vh + (kt * KT + row) * DK + c4);
        }
        __syncthreads();

        // scores s[j] = dot(Q[r,:], K[cg*8+j,:]) / 8
        float s[8] = {};
#pragma unroll
        for (int k4 = 0; k4 < DK; k4 += 4) {
            float4 q4 = *(const float4*)&Qs[r][k4];
#pragma unroll
            for (int j = 0; j < 8; ++j) {
                float4 kv = *(const float4*)&Ks[cg * 8 + j][k4];
                s[j] += q4.x * kv.x + q4.y * kv.y + q4.z * kv.z + q4.w * kv.w;
            }
        }
        const int kbase = kt * KT + cg * 8;
        float mloc = -1e30f;
#pragma unroll
        for (int j = 0; j < 8; ++j) {
            s[j] *= 0.125f;
            if (kbase + j > qg) s[j] = -1e30f;   // causal mask
            mloc = fmaxf(mloc, s[j]);
        }
        mloc = fmaxf(mloc, __shfl_xor(mloc, 1));
        mloc = fmaxf(mloc, __shfl_xor(mloc, 2));
        mloc = fmaxf(mloc, __shfl_xor(mloc, 4));
        const float mnew = fmaxf(m_i, mloc);
        const float alpha = __expf(m_i - mnew);
        float psum = 0.f;
#pragma unroll
        for (int j = 0; j < 8; ++j) {
            const float p = __expf(s[j] - mnew);
            Ps[r][cg * 8 + j] = p;
            psum += p;
        }
        psum += __shfl_xor(psum, 1);
        psum += __shfl_xor(psum, 2);
        psum += __shfl_xor(psum, 4);
        l_i = l_i * alpha + psum;
        m_i = mnew;
#pragma unroll
        for (int j = 0; j < 8; ++j) acc[j] *= alpha;
        __syncthreads();   // Ps visible to all

        // PV: acc[j] += sum_k Ps[r][k] * Vs[k][cg*8+j]
#pragma unroll 4
        for (int k = 0; k < KT; ++k) {
            const float p = Ps[r][k];
            float4 v0 = *(const float4*)&Vs[k][cg * 8];
            float4 v1 = *(const float4*)&Vs[k][cg * 8 + 4];
            acc[0] += p * v0.x; acc[1] += p * v0.y;
            acc[2] += p * v0.z; acc[3] += p * v0.w;
            acc[4] += p * v1.x; acc[5] += p * v1.y;
            acc[6] += p * v1.z; acc[7] += p * v1.w;
        }
    }

    const float inv = 1.0f / l_i;
    float* dst = Ob + (b * SEQ + qg) * DM + h * DK + cg * 8;
    *(float4*)dst = make_float4(acc[0] * inv, acc[1] * inv, acc[2] * inv, acc[3] * inv);
    *(float4*)(dst + 4) = make_float4(acc[4] * inv, acc[5] * inv, acc[6] * inv, acc[7] * inv);
}

// =====================================================================
extern "C" void kernel_launch(void* const* d_in, const int* in_sizes, int n_in,
                              void* d_out, int out_size, void* d_ws, size_t ws_size,
                              hipStream_t stream)
{
    const float* x  = (const float*)d_in[0];
    const float* Wq = (const float*)d_in[1];
    const float* Wk = (const float*)d_in[2];
    const float* Wv = (const float*)d_in[3];
    const float* Wo = (const float*)d_in[4];
    const int* pos  = (const int*)d_in[5];
    float* out = (float*)d_out;

    // Workspace: Q, K, V in (b,h,s,d) + attn in (b,s,h*d). 4 x 16 MB = 64 MB.
    float* Qb   = (float*)d_ws;
    float* Kbuf = Qb   + (size_t)MTOT * DM;
    float* Vbuf = Kbuf + (size_t)MTOT * DM;
    float* attn = Vbuf + (size_t)MTOT * DM;

    dim3 blk(256);
    proj_kernel<1><<<dim3(16, 64, 3), blk, 0, stream>>>(
        x, Wq, Wk, Wv, pos, Qb, Kbuf, Vbuf);
    attn_kernel<<<dim3(SEQ / QT, NH, BATCH), blk, 0, stream>>>(
        Qb, Kbuf, Vbuf, attn);
    proj_kernel<0><<<dim3(16, 64, 1), blk, 0, stream>>>(
        attn, Wo, nullptr, nullptr, nullptr, out, nullptr, nullptr);
}

// Round 2
// 646.490 us; speedup vs baseline: 2.4577x; 2.4577x over previous
//
#include <hip/hip_runtime.h>
#include <math.h>

#define SEQ  2048
#define DM   1024
#define NH   16
#define DK   64
#define MTOT 4096   // BATCH * SEQ
#define BATCH 2

typedef __attribute__((ext_vector_type(8))) short bf16x8;
typedef __attribute__((ext_vector_type(4))) float f32x4;

__device__ __forceinline__ ushort f2bf(float f) {
    unsigned u = __builtin_bit_cast(unsigned, f);
    u += 0x7FFFu + ((u >> 16) & 1u);   // RNE
    return (ushort)(u >> 16);
}

// =====================================================================
// Projection GEMM: C[m][n] = sum_k X[m][k] * W[n][k]   (einsum bsi,oi->bso)
// MODE 0: fp32 row-major store (final projection).
// MODE 1: blockIdx.z selects {Wq,Wk,Wv}; RoPE for mats 0,1; bf16 store
//         scattered into (b, h, s, d) layout.
// =====================================================================
template <int MODE>
__global__ __launch_bounds__(256) void proj_kernel(
    const float* __restrict__ X, const float* __restrict__ W0,
    const float* __restrict__ W1, const float* __restrict__ W2,
    const int* __restrict__ pos, void* __restrict__ out0,
    void* __restrict__ out1, void* __restrict__ out2)
{
    const int t  = threadIdx.x;
    const int bn = blockIdx.x;              // 16 N-tiles (== head index)
    const int bm = blockIdx.y;              // 64 M-tiles
    const int mat = (MODE == 1) ? blockIdx.z : 0;

    const float* __restrict__ W =
        (MODE == 1) ? (mat == 0 ? W1 : (mat == 1 ? W2 : W2)) : W0;
    // NOTE: careful selection below (W0 used in MODE 1 as Wq)
    if (MODE == 1) W = (mat == 0 ? W0 : (mat == 1 ? W1 : W2));
    void* outv = (MODE == 1) ? (mat == 0 ? out0 : (mat == 1 ? out1 : out2)) : out0;

    __shared__ float As[16][68];
    __shared__ float Bs[16][68];

    const int lrow = t >> 2;
    const int lk4  = (t & 3) * 4;
    const int tx   = t & 15, ty = t >> 4;

    const float* aptr = X + (bm * 64 + lrow) * DM + lk4;
    const float* bptr = W + (bn * 64 + lrow) * DM + lk4;

    float acc[4][4] = {};

    for (int kt = 0; kt < DM; kt += 16) {
        float4 av = *(const float4*)(aptr + kt);
        float4 bv = *(const float4*)(bptr + kt);
        __syncthreads();
        As[lk4 + 0][lrow] = av.x; As[lk4 + 1][lrow] = av.y;
        As[lk4 + 2][lrow] = av.z; As[lk4 + 3][lrow] = av.w;
        Bs[lk4 + 0][lrow] = bv.x; Bs[lk4 + 1][lrow] = bv.y;
        Bs[lk4 + 2][lrow] = bv.z; Bs[lk4 + 3][lrow] = bv.w;
        __syncthreads();
#pragma unroll
        for (int kk = 0; kk < 16; ++kk) {
            float4 a4 = *(const float4*)&As[kk][ty * 4];
            float4 b4 = *(const float4*)&Bs[kk][tx * 4];
            float a[4] = {a4.x, a4.y, a4.z, a4.w};
            float b[4] = {b4.x, b4.y, b4.z, b4.w};
#pragma unroll
            for (int i = 0; i < 4; ++i)
#pragma unroll
                for (int j = 0; j < 4; ++j) acc[i][j] += a[i] * b[j];
        }
    }

    const int m0 = bm * 64 + ty * 4;
    const int n0 = bn * 64 + tx * 4;

    if (MODE == 0) {
        float* out = (float*)outv;
#pragma unroll
        for (int i = 0; i < 4; ++i) {
            float4 v = make_float4(acc[i][0], acc[i][1], acc[i][2], acc[i][3]);
            *(float4*)&out[(m0 + i) * DM + n0] = v;
        }
    } else {
        ushort* out = (ushort*)outv;
        const int h = bn;
        const int d0 = tx * 4;
#pragma unroll
        for (int i = 0; i < 4; ++i) {
            const int m = m0 + i;
            const int b = m >> 11;
            const int sidx = m & 2047;
            ushort* dst = out + (((size_t)(b * NH + h) * SEQ + sidx) * DK) + d0;
            float vals[4];
            if (mat == 2) {
                vals[0] = acc[i][0]; vals[1] = acc[i][1];
                vals[2] = acc[i][2]; vals[3] = acc[i][3];
            } else {
                const float pf = (float)pos[sidx];
#pragma unroll
                for (int jp = 0; jp < 2; ++jp) {
                    const int dpair = d0 + 2 * jp;
                    const float freq = expf(-(float)dpair * (9.210340371976184f / 64.0f));
                    const float ang = pf * freq;
                    float sn, cs;
                    sincosf(ang, &sn, &cs);
                    const float e  = acc[i][2 * jp];
                    const float od = acc[i][2 * jp + 1];
                    vals[2 * jp]     = e * cs - od * sn;
                    vals[2 * jp + 1] = e * sn + od * cs;
                }
            }
            ushort4 sv;
            sv.x = f2bf(vals[0]); sv.y = f2bf(vals[1]);
            sv.z = f2bf(vals[2]); sv.w = f2bf(vals[3]);
            *(ushort4*)dst = sv;
        }
    }
}

// =====================================================================
// Flash attention, bf16 MFMA (16x16x32). Block = 256 thr = 4 waves,
// Q-tile 64 rows (16/wave), K-tile 64 keys. Q/K/V bf16 (b,h,s,d).
// Swizzled 1D grid for perfect causal load balance (66 K-tiles / CU).
// =====================================================================
__global__ __launch_bounds__(256, 4) void attn_mfma(
    const ushort* __restrict__ Qb, const ushort* __restrict__ Kb,
    const ushort* __restrict__ Vb, float* __restrict__ Ob)
{
    const int t    = threadIdx.x;
    const int lane = t & 63;
    const int w    = t >> 6;        // wave 0..3 (owns q rows w*16..w*16+15)
    const int l16  = lane & 15;
    const int quad = lane >> 4;     // 0..3

    // balanced swizzle: each CU's round-robin set {qt, 31-qt} x {b}
    const int id = blockIdx.x;          // 0..1023
    const int v  = id >> 8;             // 0..3
    const int u  = id & 255;
    const int h  = u & 15;
    const int p  = u >> 4;              // 0..15
    const int b  = v >> 1;
    const int qt = (v & 1) ? (31 - p) : p;

    const ushort* Qh = Qb + (size_t)((b * NH + h) * SEQ) * DK;
    const ushort* Kh = Kb + (size_t)((b * NH + h) * SEQ) * DK;
    const ushort* Vh = Vb + (size_t)((b * NH + h) * SEQ) * DK;

    __shared__ ushort Qs[64 * 72];   // [q][d]
    __shared__ ushort Ks[64 * 72];   // [k][d]
    __shared__ ushort Vt[64 * 72];   // [d][k^swz]  (transposed)
    __shared__ ushort Ps[64 * 72];   // [q][k^swz]  per-wave private rows

    // ---- stage Q tile (64x64 bf16) ----
#pragma unroll
    for (int i = 0; i < 2; ++i) {
        int f = t + i * 256;
        int row = f >> 3;
        int c8 = (f & 7) * 8;
        *(uint4*)&Qs[row * 72 + c8] = *(const uint4*)(Qh + (size_t)(qt * 64 + row) * DK + c8);
    }

    f32x4 zero4 = {0.f, 0.f, 0.f, 0.f};
    f32x4 Oacc[4];
    float m_i[4], l_i[4];
#pragma unroll
    for (int r = 0; r < 4; ++r) { m_i[r] = -1e30f; l_i[r] = 0.f; }
#pragma unroll
    for (int d = 0; d < 4; ++d) Oacc[d] = zero4;

    const float CSC = 0.18033688011112042f;  // 0.125 * log2(e)

    for (int kt = 0; kt <= qt; ++kt) {
        __syncthreads();   // prior PV reads of Ks/Vt done
        // ---- stage K tile + V tile (transposed) ----
#pragma unroll
        for (int i = 0; i < 2; ++i) {
            int f = t + i * 256;
            int row = f >> 3;              // key index within tile
            int c8 = (f & 7) * 8;          // d start
            *(uint4*)&Ks[row * 72 + c8] =
                *(const uint4*)(Kh + (size_t)(kt * 64 + row) * DK + c8);
            uint4 vv = *(const uint4*)(Vh + (size_t)(kt * 64 + row) * DK + c8);
            const ushort* vs = (const ushort*)&vv;
#pragma unroll
            for (int j = 0; j < 8; ++j) {
                int d = c8 + j;
                int col = row ^ (((d >> 3) & 3) << 4);
                Vt[d * 72 + col] = vs[j];
            }
        }
        __syncthreads();

        // ---- S = Q K^T (per-wave 16x64) ----
        f32x4 Sc[4];
#pragma unroll
        for (int ki = 0; ki < 4; ++ki) Sc[ki] = zero4;
#pragma unroll
        for (int ds = 0; ds < 2; ++ds) {
            bf16x8 aq = *(const bf16x8*)&Qs[(w * 16 + l16) * 72 + ds * 32 + quad * 8];
#pragma unroll
            for (int ki = 0; ki < 4; ++ki) {
                bf16x8 bk = *(const bf16x8*)&Ks[(ki * 16 + l16) * 72 + ds * 32 + quad * 8];
                Sc[ki] = __builtin_amdgcn_mfma_f32_16x16x32_bf16(aq, bk, Sc[ki], 0, 0, 0);
            }
        }

        // ---- online softmax (C layout: row = quad*4+r, col = l16) ----
        float ts[4][4];
        float mnew[4] = {m_i[0], m_i[1], m_i[2], m_i[3]};
        const int qbase = qt * 64 + w * 16 + quad * 4;
        const int kb    = kt * 64 + l16;
#pragma unroll
        for (int ki = 0; ki < 4; ++ki)
#pragma unroll
            for (int r = 0; r < 4; ++r) {
                float s = Sc[ki][r] * CSC;
                if (kb + ki * 16 > qbase + r) s = -1e30f;   // causal
                ts[ki][r] = s;
                mnew[r] = fmaxf(mnew[r], s);
            }
#pragma unroll
        for (int r = 0; r < 4; ++r) {
            mnew[r] = fmaxf(mnew[r], __shfl_xor(mnew[r], 1));
            mnew[r] = fmaxf(mnew[r], __shfl_xor(mnew[r], 2));
            mnew[r] = fmaxf(mnew[r], __shfl_xor(mnew[r], 4));
            mnew[r] = fmaxf(mnew[r], __shfl_xor(mnew[r], 8));
        }
        float alpha[4], psum[4];
#pragma unroll
        for (int r = 0; r < 4; ++r) {
            alpha[r] = __builtin_amdgcn_exp2f(m_i[r] - mnew[r]);
            psum[r] = 0.f;
        }
#pragma unroll
        for (int ki = 0; ki < 4; ++ki)
#pragma unroll
            for (int r = 0; r < 4; ++r) {
                float pexp = __builtin_amdgcn_exp2f(ts[ki][r] - mnew[r]);
                psum[r] += pexp;
                int col = (ki * 16 + l16) ^ (quad << 4);   // swizzle keyed on (row>>2)&3
                Ps[(w * 16 + quad * 4 + r) * 72 + col] = f2bf(pexp);
            }
#pragma unroll
        for (int r = 0; r < 4; ++r) {
            psum[r] += __shfl_xor(psum[r], 1);
            psum[r] += __shfl_xor(psum[r], 2);
            psum[r] += __shfl_xor(psum[r], 4);
            psum[r] += __shfl_xor(psum[r], 8);
            l_i[r] = l_i[r] * alpha[r] + psum[r];
            m_i[r] = mnew[r];
        }
#pragma unroll
        for (int dblk = 0; dblk < 4; ++dblk)
#pragma unroll
            for (int r = 0; r < 4; ++r)
                Oacc[dblk][r] *= alpha[r];

        // ---- O += P V  (Ps rows are wave-private; no barrier needed) ----
#pragma unroll
        for (int s = 0; s < 2; ++s) {
            int colA = (s * 32 + quad * 8) ^ (((l16 >> 2) & 3) << 4);
            bf16x8 aP = *(const bf16x8*)&Ps[(w * 16 + l16) * 72 + colA];
#pragma unroll
            for (int dblk = 0; dblk < 4; ++dblk) {
                int d = dblk * 16 + l16;
                int colV = (s * 32 + quad * 8) ^ (((d >> 3) & 3) << 4);
                bf16x8 bV = *(const bf16x8*)&Vt[d * 72 + colV];
                Oacc[dblk] = __builtin_amdgcn_mfma_f32_16x16x32_bf16(aP, bV, Oacc[dblk], 0, 0, 0);
            }
        }
    }

    // ---- epilogue: O /= l, scatter to (b, s, h*64+d) fp32 ----
    const int qrow0 = qt * 64 + w * 16 + quad * 4;
#pragma unroll
    for (int r = 0; r < 4; ++r) {
        float inv = 1.0f / l_i[r];
        float* dst = Ob + (size_t)(b * SEQ + qrow0 + r) * DM + h * DK + l16;
#pragma unroll
        for (int dblk = 0; dblk < 4; ++dblk)
            dst[dblk * 16] = Oacc[dblk][r] * inv;
    }
}

// =====================================================================
extern "C" void kernel_launch(void* const* d_in, const int* in_sizes, int n_in,
                              void* d_out, int out_size, void* d_ws, size_t ws_size,
                              hipStream_t stream)
{
    const float* x  = (const float*)d_in[0];
    const float* Wq = (const float*)d_in[1];
    const float* Wk = (const float*)d_in[2];
    const float* Wv = (const float*)d_in[3];
    const float* Wo = (const float*)d_in[4];
    const int* pos  = (const int*)d_in[5];
    float* out = (float*)d_out;

    // Workspace: Q,K,V bf16 (b,h,s,d) 8 MB each; attn fp32 (b,s,dm) 16 MB.
    ushort* Qw = (ushort*)d_ws;
    ushort* Kw = Qw + (size_t)MTOT * DM;
    ushort* Vw = Kw + (size_t)MTOT * DM;
    float* attn = (float*)(Vw + (size_t)MTOT * DM);

    dim3 blk(256);
    proj_kernel<1><<<dim3(16, 64, 3), blk, 0, stream>>>(
        x, Wq, Wk, Wv, pos, Qw, Kw, Vw);
    attn_mfma<<<dim3(1024), blk, 0, stream>>>(Qw, Kw, Vw, attn);
    proj_kernel<0><<<dim3(16, 64, 1), blk, 0, stream>>>(
        attn, Wo, nullptr, nullptr, nullptr, out, nullptr, nullptr);
}

// Round 3
// 248.294 us; speedup vs baseline: 6.3991x; 2.6037x over previous
//
#include <hip/hip_runtime.h>
#include <math.h>

#define SEQ  2048
#define DM   1024
#define NH   16
#define DK   64
#define MTOT 4096   // BATCH * SEQ
#define BATCH 2

typedef __attribute__((ext_vector_type(8))) short bf16x8;
typedef __attribute__((ext_vector_type(4))) float f32x4;

__device__ __forceinline__ ushort f2bf(float f) {
    unsigned u = __builtin_bit_cast(unsigned, f);
    u += 0x7FFFu + ((u >> 16) & 1u);   // RNE
    return (ushort)(u >> 16);
}

__device__ __forceinline__ void async_ld16(const void* g, void* l) {
    __builtin_amdgcn_global_load_lds(
        (const __attribute__((address_space(1))) void*)g,
        (__attribute__((address_space(3))) void*)l, 16, 0, 0);
}

// =====================================================================
// fp32 -> bf16 conversion: X, Wq|Wk|Wv (concat), Wo
// =====================================================================
__global__ __launch_bounds__(256) void convert_kernel(
    const float* __restrict__ X, const float* __restrict__ Wq,
    const float* __restrict__ Wk, const float* __restrict__ Wv,
    const float* __restrict__ Wo, ushort* __restrict__ Xb,
    ushort* __restrict__ Wqkvb, ushort* __restrict__ Wob)
{
    const int y = blockIdx.y;
    const float* src; ushort* dst; int n;
    if (y == 0)      { src = X;  dst = Xb;                n = MTOT * DM; }
    else if (y == 1) { src = Wq; dst = Wqkvb;             n = DM * DM; }
    else if (y == 2) { src = Wk; dst = Wqkvb + DM * DM;   n = DM * DM; }
    else if (y == 3) { src = Wv; dst = Wqkvb + 2 * DM * DM; n = DM * DM; }
    else             { src = Wo; dst = Wob;               n = DM * DM; }
    for (int i = (blockIdx.x * 256 + threadIdx.x) * 4; i < n; i += gridDim.x * 256 * 4) {
        float4 v = *(const float4*)(src + i);
        ushort4 o = { f2bf(v.x), f2bf(v.y), f2bf(v.z), f2bf(v.w) };
        *(ushort4*)(dst + i) = o;
    }
}

// =====================================================================
// bf16 MFMA GEMM: C[m][n] = sum_k A[m][k] * B[n][k]
// MODE 0 (QKV): BM=128, BN=128, wave tile 64x64. N=3072 over Wq|Wk|Wv.
//   Epilogue: RoPE for mats 0,1 (adjacent-lane pair via shfl_xor 1),
//   bf16 scatter store into (b,h,s,d).
// MODE 1 (OUT): BM=64, BN=128, wave tile 32x64. fp32 row-major store.
// K-loop: m97 structure — global_load_lds(16B) staging, 2 barriers.
// =====================================================================
template <int MODE>
__global__ __launch_bounds__(256, 3) void gemm_mfma(
    const ushort* __restrict__ Agl, const ushort* __restrict__ Bgl,
    const int* __restrict__ pos, ushort* __restrict__ Qw,
    ushort* __restrict__ Kw, ushort* __restrict__ Vw,
    float* __restrict__ Fout)
{
    constexpr int BM = (MODE == 0) ? 128 : 64;
    constexpr int BN = 128;
    constexpr int BK = 32;                 // bf16 elems per LDS row (64 B)
    constexpr int WM = (MODE == 0) ? 64 : 32;
    constexpr int MT = WM / 16;            // 4 or 2
    constexpr int NINST = (BM + BN) / 16;  // 16-row groups to stage per kt
    constexpr int PW = NINST / 4;          // wave-instructions per wave

    __shared__ __align__(16) ushort S[(BM + BN) * BK];

    const int t    = threadIdx.x;
    const int lane = t & 63;
    const int w    = t >> 6;
    const int wm   = w >> 1, wn = w & 1;
    const int l16  = lane & 15, quad = lane >> 4;
    const int lrow = lane >> 2;            // 0..15 within 16-row group
    const int lseg = (lane & 3) * 8;       // bf16 elem offset within row

    const int bn = blockIdx.x, bm = blockIdx.y;
    const int m0 = bm * BM, n0 = bn * BN;

    f32x4 acc[MT][4];
#pragma unroll
    for (int mt = 0; mt < MT; ++mt)
#pragma unroll
        for (int nt = 0; nt < 4; ++nt) acc[mt][nt] = (f32x4){0.f, 0.f, 0.f, 0.f};

    for (int kt = 0; kt < DM / BK; ++kt) {
        __syncthreads();   // prior iter's ds_reads complete before overwrite
#pragma unroll
        for (int i = 0; i < PW; ++i) {
            const int rbase = (w * PW + i) * 16;
            const ushort* g;
            if (rbase < BM)
                g = Agl + (size_t)(m0 + rbase + lrow) * DM + kt * BK + lseg;
            else
                g = Bgl + (size_t)(n0 + rbase - BM + lrow) * DM + kt * BK + lseg;
            async_ld16(g, &S[rbase * BK]);
        }
        __syncthreads();   // compiler emits vmcnt(0) drain before barrier

        bf16x8 af[MT], bfr[4];
#pragma unroll
        for (int mt = 0; mt < MT; ++mt)
            af[mt] = *(const bf16x8*)&S[(wm * WM + mt * 16 + l16) * BK + quad * 8];
#pragma unroll
        for (int nt = 0; nt < 4; ++nt)
            bfr[nt] = *(const bf16x8*)&S[(BM + wn * 64 + nt * 16 + l16) * BK + quad * 8];
#pragma unroll
        for (int mt = 0; mt < MT; ++mt)
#pragma unroll
            for (int nt = 0; nt < 4; ++nt)
                acc[mt][nt] = __builtin_amdgcn_mfma_f32_16x16x32_bf16(
                    af[mt], bfr[nt], acc[mt][nt], 0, 0, 0);
    }

    if (MODE == 1) {
        // fp32 row-major store: out[m][n]
#pragma unroll
        for (int mt = 0; mt < MT; ++mt)
#pragma unroll
            for (int r = 0; r < 4; ++r) {
                const int m = m0 + wm * WM + mt * 16 + quad * 4 + r;
#pragma unroll
                for (int nt = 0; nt < 4; ++nt) {
                    const int n = n0 + wn * 64 + nt * 16 + l16;
                    Fout[(size_t)m * DM + n] = acc[mt][nt][r];
                }
            }
    } else {
        // QKV epilogue: mat uniform per block (1024 % 128 == 0)
        const int matb = n0 >> 10;
        ushort* ob = (matb == 0) ? Qw : ((matb == 1) ? Kw : Vw);
        const int hh = ((n0 + wn * 64) >> 6) & 15;
        int dv[4]; float freqv[4];
#pragma unroll
        for (int nt = 0; nt < 4; ++nt) {
            dv[nt] = nt * 16 + l16;
            const int dpair = dv[nt] & ~1;
            // 10000^(-dpair/64) = 2^(-dpair * log2(10000)/64)
            freqv[nt] = exp2f(-(float)dpair * (13.287712379549449f / 64.0f));
        }
#pragma unroll
        for (int mt = 0; mt < MT; ++mt)
#pragma unroll
            for (int r = 0; r < 4; ++r) {
                const int m = m0 + wm * WM + mt * 16 + quad * 4 + r;
                const int s = m & 2047;
                const int b = m >> 11;
                const float pf = (float)pos[s];
                ushort* rowp = ob + ((size_t)(b * NH + hh) * SEQ + s) * DK;
#pragma unroll
                for (int nt = 0; nt < 4; ++nt) {
                    const float v = acc[mt][nt][r];
                    const float vp = __shfl_xor(v, 1);   // RoPE partner (d^1)
                    float res;
                    if (matb == 2) {
                        res = v;
                    } else {
                        float sn, cs;
                        sincosf(pf * freqv[nt], &sn, &cs);
                        res = (dv[nt] & 1) ? (vp * sn + v * cs) : (v * cs - vp * sn);
                    }
                    rowp[dv[nt]] = f2bf(res);
                }
            }
    }
}

// =====================================================================
// Flash attention, bf16 MFMA (16x16x32). Block = 4 waves, Q-tile 64,
// K-tile 64. Epilogue writes bf16 to attn buffer (b, s, h*64+d).
// =====================================================================
__global__ __launch_bounds__(256, 4) void attn_mfma(
    const ushort* __restrict__ Qb, const ushort* __restrict__ Kb,
    const ushort* __restrict__ Vb, ushort* __restrict__ Ob)
{
    const int t    = threadIdx.x;
    const int lane = t & 63;
    const int w    = t >> 6;
    const int l16  = lane & 15;
    const int quad = lane >> 4;

    const int id = blockIdx.x;
    const int v  = id >> 8;
    const int u  = id & 255;
    const int h  = u & 15;
    const int p  = u >> 4;
    const int b  = v >> 1;
    const int qt = (v & 1) ? (31 - p) : p;

    const ushort* Qh = Qb + (size_t)((b * NH + h) * SEQ) * DK;
    const ushort* Kh = Kb + (size_t)((b * NH + h) * SEQ) * DK;
    const ushort* Vh = Vb + (size_t)((b * NH + h) * SEQ) * DK;

    __shared__ ushort Qs[64 * 72];
    __shared__ ushort Ks[64 * 72];
    __shared__ ushort Vt[64 * 72];
    __shared__ ushort Ps[64 * 72];

#pragma unroll
    for (int i = 0; i < 2; ++i) {
        int f = t + i * 256;
        int row = f >> 3;
        int c8 = (f & 7) * 8;
        *(uint4*)&Qs[row * 72 + c8] = *(const uint4*)(Qh + (size_t)(qt * 64 + row) * DK + c8);
    }

    f32x4 zero4 = {0.f, 0.f, 0.f, 0.f};
    f32x4 Oacc[4];
    float m_i[4], l_i[4];
#pragma unroll
    for (int r = 0; r < 4; ++r) { m_i[r] = -1e30f; l_i[r] = 0.f; }
#pragma unroll
    for (int d = 0; d < 4; ++d) Oacc[d] = zero4;

    const float CSC = 0.18033688011112042f;  // 0.125 * log2(e)

    for (int kt = 0; kt <= qt; ++kt) {
        __syncthreads();
#pragma unroll
        for (int i = 0; i < 2; ++i) {
            int f = t + i * 256;
            int row = f >> 3;
            int c8 = (f & 7) * 8;
            *(uint4*)&Ks[row * 72 + c8] =
                *(const uint4*)(Kh + (size_t)(kt * 64 + row) * DK + c8);
            uint4 vv = *(const uint4*)(Vh + (size_t)(kt * 64 + row) * DK + c8);
            const ushort* vs = (const ushort*)&vv;
#pragma unroll
            for (int j = 0; j < 8; ++j) {
                int d = c8 + j;
                int col = row ^ (((d >> 3) & 3) << 4);
                Vt[d * 72 + col] = vs[j];
            }
        }
        __syncthreads();

        f32x4 Sc[4];
#pragma unroll
        for (int ki = 0; ki < 4; ++ki) Sc[ki] = zero4;
#pragma unroll
        for (int ds = 0; ds < 2; ++ds) {
            bf16x8 aq = *(const bf16x8*)&Qs[(w * 16 + l16) * 72 + ds * 32 + quad * 8];
#pragma unroll
            for (int ki = 0; ki < 4; ++ki) {
                bf16x8 bk = *(const bf16x8*)&Ks[(ki * 16 + l16) * 72 + ds * 32 + quad * 8];
                Sc[ki] = __builtin_amdgcn_mfma_f32_16x16x32_bf16(aq, bk, Sc[ki], 0, 0, 0);
            }
        }

        float ts[4][4];
        float mnew[4] = {m_i[0], m_i[1], m_i[2], m_i[3]};
        const int qbase = qt * 64 + w * 16 + quad * 4;
        const int kb    = kt * 64 + l16;
#pragma unroll
        for (int ki = 0; ki < 4; ++ki)
#pragma unroll
            for (int r = 0; r < 4; ++r) {
                float s = Sc[ki][r] * CSC;
                if (kb + ki * 16 > qbase + r) s = -1e30f;
                ts[ki][r] = s;
                mnew[r] = fmaxf(mnew[r], s);
            }
#pragma unroll
        for (int r = 0; r < 4; ++r) {
            mnew[r] = fmaxf(mnew[r], __shfl_xor(mnew[r], 1));
            mnew[r] = fmaxf(mnew[r], __shfl_xor(mnew[r], 2));
            mnew[r] = fmaxf(mnew[r], __shfl_xor(mnew[r], 4));
            mnew[r] = fmaxf(mnew[r], __shfl_xor(mnew[r], 8));
        }
        float alpha[4], psum[4];
#pragma unroll
        for (int r = 0; r < 4; ++r) {
            alpha[r] = __builtin_amdgcn_exp2f(m_i[r] - mnew[r]);
            psum[r] = 0.f;
        }
#pragma unroll
        for (int ki = 0; ki < 4; ++ki)
#pragma unroll
            for (int r = 0; r < 4; ++r) {
                float pexp = __builtin_amdgcn_exp2f(ts[ki][r] - mnew[r]);
                psum[r] += pexp;
                int col = (ki * 16 + l16) ^ (quad << 4);
                Ps[(w * 16 + quad * 4 + r) * 72 + col] = f2bf(pexp);
            }
#pragma unroll
        for (int r = 0; r < 4; ++r) {
            psum[r] += __shfl_xor(psum[r], 1);
            psum[r] += __shfl_xor(psum[r], 2);
            psum[r] += __shfl_xor(psum[r], 4);
            psum[r] += __shfl_xor(psum[r], 8);
            l_i[r] = l_i[r] * alpha[r] + psum[r];
            m_i[r] = mnew[r];
        }
#pragma unroll
        for (int dblk = 0; dblk < 4; ++dblk)
#pragma unroll
            for (int r = 0; r < 4; ++r)
                Oacc[dblk][r] *= alpha[r];

#pragma unroll
        for (int s = 0; s < 2; ++s) {
            int colA = (s * 32 + quad * 8) ^ (((l16 >> 2) & 3) << 4);
            bf16x8 aP = *(const bf16x8*)&Ps[(w * 16 + l16) * 72 + colA];
#pragma unroll
            for (int dblk = 0; dblk < 4; ++dblk) {
                int d = dblk * 16 + l16;
                int colV = (s * 32 + quad * 8) ^ (((d >> 3) & 3) << 4);
                bf16x8 bV = *(const bf16x8*)&Vt[d * 72 + colV];
                Oacc[dblk] = __builtin_amdgcn_mfma_f32_16x16x32_bf16(aP, bV, Oacc[dblk], 0, 0, 0);
            }
        }
    }

    const int qrow0 = qt * 64 + w * 16 + quad * 4;
#pragma unroll
    for (int r = 0; r < 4; ++r) {
        float inv = 1.0f / l_i[r];
        ushort* dst = Ob + (size_t)(b * SEQ + qrow0 + r) * DM + h * DK + l16;
#pragma unroll
        for (int dblk = 0; dblk < 4; ++dblk)
            dst[dblk * 16] = f2bf(Oacc[dblk][r] * inv);
    }
}

// =====================================================================
extern "C" void kernel_launch(void* const* d_in, const int* in_sizes, int n_in,
                              void* d_out, int out_size, void* d_ws, size_t ws_size,
                              hipStream_t stream)
{
    const float* x  = (const float*)d_in[0];
    const float* Wq = (const float*)d_in[1];
    const float* Wk = (const float*)d_in[2];
    const float* Wv = (const float*)d_in[3];
    const float* Wo = (const float*)d_in[4];
    const int* pos  = (const int*)d_in[5];
    float* out = (float*)d_out;

    // Workspace (bf16): Xb 8MB | Wqkv 6MB | Wob 2MB | Q,K,V 8MB ea | attn 8MB
    ushort* Xb    = (ushort*)d_ws;
    ushort* Wqkvb = Xb + (size_t)MTOT * DM;
    ushort* Wob   = Wqkvb + (size_t)3 * DM * DM;
    ushort* Qw    = Wob + (size_t)DM * DM;
    ushort* Kw    = Qw + (size_t)MTOT * DM;
    ushort* Vw    = Kw + (size_t)MTOT * DM;
    ushort* attnb = Vw + (size_t)MTOT * DM;

    dim3 blk(256);
    convert_kernel<<<dim3(1024, 5), blk, 0, stream>>>(
        x, Wq, Wk, Wv, Wo, Xb, Wqkvb, Wob);
    // QKV: M=4096, N=3072 -> grid (3072/128, 4096/128)
    gemm_mfma<0><<<dim3(24, 32), blk, 0, stream>>>(
        Xb, Wqkvb, pos, Qw, Kw, Vw, nullptr);
    attn_mfma<<<dim3(1024), blk, 0, stream>>>(Qw, Kw, Vw, attnb);
    // OUT: M=4096, N=1024 -> grid (1024/128, 4096/64)
    gemm_mfma<1><<<dim3(8, 64), blk, 0, stream>>>(
        attnb, Wob, pos, nullptr, nullptr, nullptr, out);
}

// Round 4
// 220.521 us; speedup vs baseline: 7.2050x; 1.1259x over previous
//
#include <hip/hip_runtime.h>
#include <math.h>

#define SEQ  2048
#define DM   1024
#define NH   16
#define DK   64
#define MTOT 4096   // BATCH * SEQ
#define BATCH 2

typedef __attribute__((ext_vector_type(8))) short bf16x8;
typedef __attribute__((ext_vector_type(4))) float f32x4;

__device__ __forceinline__ ushort f2bf(float f) {
    unsigned u = __builtin_bit_cast(unsigned, f);
    u += 0x7FFFu + ((u >> 16) & 1u);   // RNE
    return (ushort)(u >> 16);
}

__device__ __forceinline__ void async_ld16(const void* g, void* l) {
    __builtin_amdgcn_global_load_lds(
        (const __attribute__((address_space(1))) void*)g,
        (__attribute__((address_space(3))) void*)l, 16, 0, 0);
}

// Image layouts (per b,h: 32 tiles x 4096 ushort, one 64x64 tile each):
//   Q/K image: element (tile, row=token_local, d):
//     off = tile*4096 + row*64 + (((d>>3) ^ (row&7))<<3) + (d&7)
//   V image (transposed): element (tile, row=d, key_local k):
//     off = tile*4096 + d*64 + (((k>>3) ^ (d&7))<<3) + (k&7)
// The XOR swizzle makes the attention kernel's b128 LDS fragment reads
// bandwidth-minimal (2-way max per bank group) with a FLAT LDS copy,
// so staging can be pure global_load_lds (wave-uniform dest).

// =====================================================================
// convert: fp32 -> bf16 for X, Wq|Wk (concat), Wv, Wo; plus RoPE table
// =====================================================================
__global__ __launch_bounds__(256) void convert_kernel(
    const float* __restrict__ X, const float* __restrict__ Wq,
    const float* __restrict__ Wk, const float* __restrict__ Wv,
    const float* __restrict__ Wo, const int* __restrict__ pos,
    ushort* __restrict__ Xb, ushort* __restrict__ Wqkb,
    ushort* __restrict__ Wvb, ushort* __restrict__ Wob,
    float2* __restrict__ rtab)
{
    const int y = blockIdx.y;
    if (y == 5) {
        // rope table: rtab[s*32 + j] = (cos, sin)(pos[s] * 10000^(-2j/64))
        int i = blockIdx.x * 256 + threadIdx.x;
        if (i < SEQ * 32) {
            int s = i >> 5, j = i & 31;
            float freq = exp2f(-(float)(2 * j) * (13.287712379549449f / 64.0f));
            float ang = (float)pos[s] * freq;
            float sn, cs;
            sincosf(ang, &sn, &cs);
            rtab[i] = make_float2(cs, sn);
        }
        return;
    }
    const float* src; ushort* dst; int n;
    if (y == 0)      { src = X;  dst = Xb;             n = MTOT * DM; }
    else if (y == 1) { src = Wq; dst = Wqkb;           n = DM * DM; }
    else if (y == 2) { src = Wk; dst = Wqkb + DM * DM; n = DM * DM; }
    else if (y == 3) { src = Wv; dst = Wvb;            n = DM * DM; }
    else             { src = Wo; dst = Wob;            n = DM * DM; }
    for (int i = (blockIdx.x * 256 + threadIdx.x) * 4; i < n; i += gridDim.x * 256 * 4) {
        float4 v = *(const float4*)(src + i);
        ushort4 o = { f2bf(v.x), f2bf(v.y), f2bf(v.z), f2bf(v.w) };
        *(ushort4*)(dst + i) = o;
    }
}

// =====================================================================
// bf16 MFMA GEMM: C[m][n] = sum_k A[m][k] * B[n][k], K = 1024.
// MODE 0 (QK):  BM=128,BN=128. B = Wq|Wk. Epilogue: RoPE (table) +
//               swizzled Q/K-image store.
// MODE 1 (OUT): BM=64,BN=128. fp32 row-major store.
// MODE 2 (V^T): BM=64 (d rows, A=Wv), BN=128 (tokens, B=X).
//               Epilogue: swizzled V-image store.
// =====================================================================
template <int MODE>
__global__ __launch_bounds__(256, 3) void gemm_mfma(
    const ushort* __restrict__ Agl, const ushort* __restrict__ Bgl,
    const float2* __restrict__ rtab, ushort* __restrict__ O0,
    ushort* __restrict__ O1, float* __restrict__ Fout)
{
    constexpr int BM = (MODE == 0) ? 128 : 64;
    constexpr int BN = 128;
    constexpr int BK = 32;
    constexpr int WM = (MODE == 0) ? 64 : 32;
    constexpr int MT = WM / 16;
    constexpr int NINST = (BM + BN) / 16;
    constexpr int PW = NINST / 4;

    __shared__ __align__(16) ushort S[(BM + BN) * BK];

    const int t    = threadIdx.x;
    const int lane = t & 63;
    const int w    = t >> 6;
    const int wm   = w >> 1, wn = w & 1;
    const int l16  = lane & 15, quad = lane >> 4;
    const int lrow = lane >> 2;
    const int lseg = (lane & 3) * 8;

    const int bn = blockIdx.x, bm = blockIdx.y;
    const int m0 = bm * BM, n0 = bn * BN;

    f32x4 acc[MT][4];
#pragma unroll
    for (int mt = 0; mt < MT; ++mt)
#pragma unroll
        for (int nt = 0; nt < 4; ++nt) acc[mt][nt] = (f32x4){0.f, 0.f, 0.f, 0.f};

    for (int kt = 0; kt < DM / BK; ++kt) {
        __syncthreads();
#pragma unroll
        for (int i = 0; i < PW; ++i) {
            const int rbase = (w * PW + i) * 16;
            const ushort* g;
            if (rbase < BM)
                g = Agl + (size_t)(m0 + rbase + lrow) * DM + kt * BK + lseg;
            else
                g = Bgl + (size_t)(n0 + rbase - BM + lrow) * DM + kt * BK + lseg;
            async_ld16(g, &S[rbase * BK]);
        }
        __syncthreads();

        bf16x8 af[MT], bfr[4];
#pragma unroll
        for (int mt = 0; mt < MT; ++mt)
            af[mt] = *(const bf16x8*)&S[(wm * WM + mt * 16 + l16) * BK + quad * 8];
#pragma unroll
        for (int nt = 0; nt < 4; ++nt)
            bfr[nt] = *(const bf16x8*)&S[(BM + wn * 64 + nt * 16 + l16) * BK + quad * 8];
#pragma unroll
        for (int mt = 0; mt < MT; ++mt)
#pragma unroll
            for (int nt = 0; nt < 4; ++nt)
                acc[mt][nt] = __builtin_amdgcn_mfma_f32_16x16x32_bf16(
                    af[mt], bfr[nt], acc[mt][nt], 0, 0, 0);
    }

    if (MODE == 1) {
#pragma unroll
        for (int mt = 0; mt < MT; ++mt)
#pragma unroll
            for (int r = 0; r < 4; ++r) {
                const int m = m0 + wm * WM + mt * 16 + quad * 4 + r;
#pragma unroll
                for (int nt = 0; nt < 4; ++nt) {
                    const int n = n0 + wn * 64 + nt * 16 + l16;
                    Fout[(size_t)m * DM + n] = acc[mt][nt][r];
                }
            }
    } else if (MODE == 0) {
        const int matb = n0 >> 10;                       // 0 = Q, 1 = K
        ushort* img = matb ? O1 : O0;
        const int hh = ((n0 & 1023) + wn * 64) >> 6;
        int dloc[4];
#pragma unroll
        for (int nt = 0; nt < 4; ++nt) dloc[nt] = nt * 16 + l16;
#pragma unroll
        for (int mt = 0; mt < MT; ++mt)
#pragma unroll
            for (int r = 0; r < 4; ++r) {
                const int m = m0 + wm * WM + mt * 16 + quad * 4 + r;
                const int bb = m >> 11;
                const int s = m & 2047;
                const size_t base =
                    ((size_t)(bb * NH + hh) * 32 + (s >> 6)) * 4096 + (s & 63) * 64;
                const int swz = s & 7;
#pragma unroll
                for (int nt = 0; nt < 4; ++nt) {
                    const float v = acc[mt][nt][r];
                    const float vp = __shfl_xor(v, 1);
                    const float2 cs = rtab[s * 32 + (dloc[nt] >> 1)];
                    const float res = (dloc[nt] & 1) ? (vp * cs.y + v * cs.x)
                                                     : (v * cs.x - vp * cs.y);
                    const int d = dloc[nt];
                    img[base + (((d >> 3) ^ swz) << 3) + (d & 7)] = f2bf(res);
                }
            }
    } else {
        // MODE 2: m index = d_global, n index = token
#pragma unroll
        for (int mt = 0; mt < MT; ++mt)
#pragma unroll
            for (int r = 0; r < 4; ++r) {
                const int dg = m0 + wm * WM + mt * 16 + quad * 4 + r;
                const int hh = dg >> 6, dd = dg & 63;
                const int swzd = dd & 7;
#pragma unroll
                for (int nt = 0; nt < 4; ++nt) {
                    const int token = n0 + wn * 64 + nt * 16 + l16;
                    const int bb = token >> 11;
                    const int s = token & 2047;
                    const size_t off =
                        ((size_t)(bb * NH + hh) * 32 + (s >> 6)) * 4096 + dd * 64 +
                        ((((s & 63) >> 3) ^ swzd) << 3) + (s & 7);
                    O0[off] = f2bf(acc[mt][nt][r]);
                }
            }
    }
}

// =====================================================================
// Flash attention: bf16 MFMA, image-layout inputs, pure async staging,
// single-barrier double-buffered K/V prefetch, row-sum via MFMA ones-col.
// Block = 4 waves, Q-tile 64 (16 rows/wave), K-tile 64.
// =====================================================================
__global__ __launch_bounds__(256, 3) void attn_mfma(
    const ushort* __restrict__ Qimg, const ushort* __restrict__ Kimg,
    const ushort* __restrict__ Vimg, ushort* __restrict__ Ob)
{
    const int t    = threadIdx.x;
    const int lane = t & 63;
    const int w    = t >> 6;
    const int l16  = lane & 15;
    const int quad = lane >> 4;

    // balanced swizzle: pair {p, 31-p} per CU
    const int id = blockIdx.x;
    const int v  = id >> 8;
    const int u  = id & 255;
    const int h  = u & 15;
    const int p  = u >> 4;
    const int b  = v >> 1;
    const int qt = (v & 1) ? (31 - p) : p;

    const size_t bh = ((size_t)(b * NH + h)) * 32;
    const ushort* Qt = Qimg + (bh + qt) * 4096;
    const ushort* Kh = Kimg + bh * 4096;
    const ushort* Vh = Vimg + bh * 4096;

    __shared__ __align__(16) ushort Qs[4096];
    __shared__ __align__(16) ushort Ks[2][4096];
    __shared__ __align__(16) ushort Vs[2][5120];   // 64 data rows + 16 ones/zero rows
    __shared__ __align__(16) ushort Ps[4096];

    // ones row (d=64) = 1.0 bf16, rows 65..79 = 0 — flat region [4096,5120)
    for (int j = t; j < 1024; j += 256) {
        ushort vv = (j < 64) ? (ushort)0x3F80 : (ushort)0;
        Vs[0][4096 + j] = vv;
        Vs[1][4096 + j] = vv;
    }

    // stage Q (flat 8 KB copy; swizzle baked into image)
    async_ld16(Qt + (w * 64 + lane) * 8,        &Qs[w * 512]);
    async_ld16(Qt + ((4 + w) * 64 + lane) * 8,  &Qs[(4 + w) * 512]);

    // prefetch tile 0
    {
        const ushort* Kt = Kh;
        const ushort* Vt = Vh;
        async_ld16(Kt + (w * 64 + lane) * 8,       &Ks[0][w * 512]);
        async_ld16(Kt + ((4 + w) * 64 + lane) * 8, &Ks[0][(4 + w) * 512]);
        async_ld16(Vt + (w * 64 + lane) * 8,       &Vs[0][w * 512]);
        async_ld16(Vt + ((4 + w) * 64 + lane) * 8, &Vs[0][(4 + w) * 512]);
    }

    f32x4 zero4 = {0.f, 0.f, 0.f, 0.f};
    f32x4 Oacc[4], Lacc = zero4;
    float m_i[4];
#pragma unroll
    for (int r = 0; r < 4; ++r) m_i[r] = -1e30f;
#pragma unroll
    for (int d = 0; d < 4; ++d) Oacc[d] = zero4;

    const float CSC = 0.18033688011112042f;  // (1/8) * log2(e)
    const int swz    = l16 & 7;
    const int qrow_l = w * 16 + l16;         // A-frag row (local)
    const int arow   = w * 16 + quad * 4;    // C-layout row base (local)
    const int rswz0  = (quad * 4) & 7;

    for (int kt = 0; kt <= qt; ++kt) {
        const int cur = kt & 1;
        __syncthreads();   // drains tile-kt async loads; guards LDS buffer reuse

        if (kt < qt) {     // prefetch kt+1 into the other buffer (post-barrier!)
            const ushort* Kt = Kh + (size_t)(kt + 1) * 4096;
            const ushort* Vt = Vh + (size_t)(kt + 1) * 4096;
            const int nb = cur ^ 1;
            async_ld16(Kt + (w * 64 + lane) * 8,       &Ks[nb][w * 512]);
            async_ld16(Kt + ((4 + w) * 64 + lane) * 8, &Ks[nb][(4 + w) * 512]);
            async_ld16(Vt + (w * 64 + lane) * 8,       &Vs[nb][w * 512]);
            async_ld16(Vt + ((4 + w) * 64 + lane) * 8, &Vs[nb][(4 + w) * 512]);
        }

        // ---- S = Q K^T ----
        f32x4 Sc[4];
#pragma unroll
        for (int ki = 0; ki < 4; ++ki) Sc[ki] = zero4;
#pragma unroll
        for (int ds = 0; ds < 2; ++ds) {
            const int slot = (((ds * 4 + quad) ^ swz) << 3);
            bf16x8 aq = *(const bf16x8*)&Qs[qrow_l * 64 + slot];
#pragma unroll
            for (int ki = 0; ki < 4; ++ki) {
                bf16x8 bk = *(const bf16x8*)&Ks[cur][(ki * 16 + l16) * 64 + slot];
                Sc[ki] = __builtin_amdgcn_mfma_f32_16x16x32_bf16(aq, bk, Sc[ki], 0, 0, 0);
            }
        }

        // ---- online softmax (no psum shuffles; l via ones-column MFMA) ----
        float ts[4][4];
        float mnew[4] = {m_i[0], m_i[1], m_i[2], m_i[3]};
        if (kt == qt) {   // only the diagonal tile needs masking
#pragma unroll
            for (int ki = 0; ki < 4; ++ki)
#pragma unroll
                for (int r = 0; r < 4; ++r) {
                    float sv = Sc[ki][r] * CSC;
                    if (ki * 16 + l16 > arow + r) sv = -1e30f;
                    ts[ki][r] = sv;
                    mnew[r] = fmaxf(mnew[r], sv);
                }
        } else {
#pragma unroll
            for (int ki = 0; ki < 4; ++ki)
#pragma unroll
                for (int r = 0; r < 4; ++r) {
                    float sv = Sc[ki][r] * CSC;
                    ts[ki][r] = sv;
                    mnew[r] = fmaxf(mnew[r], sv);
                }
        }
#pragma unroll
        for (int r = 0; r < 4; ++r) {
            mnew[r] = fmaxf(mnew[r], __shfl_xor(mnew[r], 1));
            mnew[r] = fmaxf(mnew[r], __shfl_xor(mnew[r], 2));
            mnew[r] = fmaxf(mnew[r], __shfl_xor(mnew[r], 4));
            mnew[r] = fmaxf(mnew[r], __shfl_xor(mnew[r], 8));
        }
        float alpha[4];
#pragma unroll
        for (int r = 0; r < 4; ++r) {
            alpha[r] = __builtin_amdgcn_exp2f(m_i[r] - mnew[r]);
            m_i[r] = mnew[r];
        }
#pragma unroll
        for (int dblk = 0; dblk < 4; ++dblk)
#pragma unroll
            for (int r = 0; r < 4; ++r) Oacc[dblk][r] *= alpha[r];
#pragma unroll
        for (int r = 0; r < 4; ++r) Lacc[r] *= alpha[r];

        // P -> LDS (A-operand layout, swizzled; wave-private rows)
#pragma unroll
        for (int ki = 0; ki < 4; ++ki)
#pragma unroll
            for (int r = 0; r < 4; ++r) {
                float pexp = __builtin_amdgcn_exp2f(ts[ki][r] - mnew[r]);
                const int slotp =
                    ((((ki * 2 + (l16 >> 3)) ^ ((rswz0 + r) & 7)) << 3)) + (l16 & 7);
                Ps[(arow + r) * 64 + slotp] = f2bf(pexp);
            }

        // ---- O += P V ; L += P * ones ----
#pragma unroll
        for (int s2 = 0; s2 < 2; ++s2) {
            const int slotv = (((s2 * 4 + quad) ^ swz) << 3);
            bf16x8 aP = *(const bf16x8*)&Ps[qrow_l * 64 + slotv];
#pragma unroll
            for (int dblk = 0; dblk < 4; ++dblk) {
                bf16x8 bV = *(const bf16x8*)&Vs[cur][(dblk * 16 + l16) * 64 + slotv];
                Oacc[dblk] = __builtin_amdgcn_mfma_f32_16x16x32_bf16(aP, bV, Oacc[dblk], 0, 0, 0);
            }
            bf16x8 bO = *(const bf16x8*)&Vs[cur][(64 + l16) * 64 + slotv];
            Lacc = __builtin_amdgcn_mfma_f32_16x16x32_bf16(aP, bO, Lacc, 0, 0, 0);
        }
    }

    // ---- epilogue: l lives in lanes l16==0 (col 0); broadcast, divide, store ----
    const int qrow0 = qt * 64 + arow;
#pragma unroll
    for (int r = 0; r < 4; ++r) {
        const float lsum = __shfl(Lacc[r], lane & 48);
        const float inv = 1.0f / lsum;
        ushort* dst = Ob + (size_t)(b * SEQ + qrow0 + r) * DM + h * DK + l16;
#pragma unroll
        for (int dblk = 0; dblk < 4; ++dblk)
            dst[dblk * 16] = f2bf(Oacc[dblk][r] * inv);
    }
}

// =====================================================================
extern "C" void kernel_launch(void* const* d_in, const int* in_sizes, int n_in,
                              void* d_out, int out_size, void* d_ws, size_t ws_size,
                              hipStream_t stream)
{
    const float* x  = (const float*)d_in[0];
    const float* Wq = (const float*)d_in[1];
    const float* Wk = (const float*)d_in[2];
    const float* Wv = (const float*)d_in[3];
    const float* Wo = (const float*)d_in[4];
    const int* pos  = (const int*)d_in[5];
    float* out = (float*)d_out;

    ushort* Xb    = (ushort*)d_ws;                    // 4096x1024
    ushort* Wqkb  = Xb + (size_t)MTOT * DM;           // 2048x1024 (Wq|Wk)
    ushort* Wvb   = Wqkb + (size_t)2 * DM * DM;       // 1024x1024
    ushort* Wob   = Wvb + (size_t)DM * DM;            // 1024x1024
    float2* rtab  = (float2*)(Wob + (size_t)DM * DM); // 2048*32 float2
    ushort* Qimg  = (ushort*)(rtab + SEQ * 32);
    ushort* Kimg  = Qimg + (size_t)MTOT * DM;
    ushort* Vimg  = Kimg + (size_t)MTOT * DM;
    ushort* attnb = Vimg + (size_t)MTOT * DM;

    dim3 blk(256);
    convert_kernel<<<dim3(1024, 6), blk, 0, stream>>>(
        x, Wq, Wk, Wv, Wo, pos, Xb, Wqkb, Wvb, Wob, rtab);
    // QK: M=4096 tokens, N=2048 (Wq|Wk)
    gemm_mfma<0><<<dim3(16, 32), blk, 0, stream>>>(
        Xb, Wqkb, rtab, Qimg, Kimg, nullptr);
    // V^T: M=1024 d-rows (A=Wv), N=4096 tokens (B=X)
    gemm_mfma<2><<<dim3(32, 16), blk, 0, stream>>>(
        Wvb, Xb, nullptr, Vimg, nullptr, nullptr);
    attn_mfma<<<dim3(1024), blk, 0, stream>>>(Qimg, Kimg, Vimg, attnb);
    // OUT: M=4096, N=1024, fp32
    gemm_mfma<1><<<dim3(8, 64), blk, 0, stream>>>(
        attnb, Wob, nullptr, nullptr, nullptr, out);
}

// Round 5
// 214.161 us; speedup vs baseline: 7.4190x; 1.0297x over previous
//
#include <hip/hip_runtime.h>
#include <math.h>

#define SEQ  2048
#define DM   1024
#define NH   16
#define DK   64
#define MTOT 4096   // BATCH * SEQ
#define BATCH 2

typedef __attribute__((ext_vector_type(8))) short bf16x8;
typedef __attribute__((ext_vector_type(4))) float f32x4;

#define CSC 0.18033688011112042f   // 0.125 * log2(e), folded into Q image

__device__ __forceinline__ ushort f2bf(float f) {
    unsigned u = __builtin_bit_cast(unsigned, f);
    u += 0x7FFFu + ((u >> 16) & 1u);   // RNE
    return (ushort)(u >> 16);
}

__device__ __forceinline__ void async_ld16(const void* g, void* l) {
    __builtin_amdgcn_global_load_lds(
        (const __attribute__((address_space(1))) void*)g,
        (__attribute__((address_space(3))) void*)l, 16, 0, 0);
}

// Image layouts (per b,h: 32 tiles x 4096 ushort, one 64x64 tile each):
//   Q/K image: (tile, row=token_local, d):
//     off = tile*4096 + row*64 + (((d>>3) ^ (row&7))<<3) + (d&7)
//   V image (transposed): (tile, row=d, key_local k):
//     off = tile*4096 + d*64 + (((k>>3) ^ (d&7))<<3) + (k&7)
// XOR swizzle => all attention LDS b128 frag reads are conflict-free
// (verified R4: SQ_LDS_BANK_CONFLICT == 0) with FLAT global_load_lds staging.
// Q image values are pre-scaled by CSC (softmax scale in log2 space).

// =====================================================================
// convert: fp32 -> bf16 for X, Wq|Wk (concat), Wv, Wo; plus RoPE table
// =====================================================================
__global__ __launch_bounds__(256) void convert_kernel(
    const float* __restrict__ X, const float* __restrict__ Wq,
    const float* __restrict__ Wk, const float* __restrict__ Wv,
    const float* __restrict__ Wo, const int* __restrict__ pos,
    ushort* __restrict__ Xb, ushort* __restrict__ Wqkb,
    ushort* __restrict__ Wvb, ushort* __restrict__ Wob,
    float2* __restrict__ rtab)
{
    const int y = blockIdx.y;
    if (y == 5) {
        int i = blockIdx.x * 256 + threadIdx.x;
        if (i < SEQ * 32) {
            int s = i >> 5, j = i & 31;
            float freq = exp2f(-(float)(2 * j) * (13.287712379549449f / 64.0f));
            float ang = (float)pos[s] * freq;
            float sn, cs;
            sincosf(ang, &sn, &cs);
            rtab[i] = make_float2(cs, sn);
        }
        return;
    }
    const float* src; ushort* dst; int n;
    if (y == 0)      { src = X;  dst = Xb;             n = MTOT * DM; }
    else if (y == 1) { src = Wq; dst = Wqkb;           n = DM * DM; }
    else if (y == 2) { src = Wk; dst = Wqkb + DM * DM; n = DM * DM; }
    else if (y == 3) { src = Wv; dst = Wvb;            n = DM * DM; }
    else             { src = Wo; dst = Wob;            n = DM * DM; }
    for (int i = (blockIdx.x * 256 + threadIdx.x) * 4; i < n; i += gridDim.x * 256 * 4) {
        float4 v = *(const float4*)(src + i);
        ushort4 o = { f2bf(v.x), f2bf(v.y), f2bf(v.z), f2bf(v.w) };
        *(ushort4*)(dst + i) = o;
    }
}

// =====================================================================
// bf16 MFMA GEMM: C[m][n] = sum_k A[m][k] * B[n][k], K = 1024.
// MODE 0 (QK):  BM=128,BN=128. B = Wq|Wk. Epilogue: RoPE (table) +
//               swizzled Q/K-image store; Q additionally scaled by CSC.
// MODE 1 (OUT): BM=64,BN=128. fp32 row-major store.
// MODE 2 (V^T): BM=64 (d rows, A=Wv), BN=128 (tokens, B=X).
//               Epilogue: swizzled V-image store.
// =====================================================================
template <int MODE>
__global__ __launch_bounds__(256, 3) void gemm_mfma(
    const ushort* __restrict__ Agl, const ushort* __restrict__ Bgl,
    const float2* __restrict__ rtab, ushort* __restrict__ O0,
    ushort* __restrict__ O1, float* __restrict__ Fout)
{
    constexpr int BM = (MODE == 0) ? 128 : 64;
    constexpr int BN = 128;
    constexpr int BK = 32;
    constexpr int WM = (MODE == 0) ? 64 : 32;
    constexpr int MT = WM / 16;
    constexpr int NINST = (BM + BN) / 16;
    constexpr int PW = NINST / 4;

    __shared__ __align__(16) ushort S[(BM + BN) * BK];

    const int t    = threadIdx.x;
    const int lane = t & 63;
    const int w    = t >> 6;
    const int wm   = w >> 1, wn = w & 1;
    const int l16  = lane & 15, quad = lane >> 4;
    const int lrow = lane >> 2;
    const int lseg = (lane & 3) * 8;

    const int bn = blockIdx.x, bm = blockIdx.y;
    const int m0 = bm * BM, n0 = bn * BN;

    f32x4 acc[MT][4];
#pragma unroll
    for (int mt = 0; mt < MT; ++mt)
#pragma unroll
        for (int nt = 0; nt < 4; ++nt) acc[mt][nt] = (f32x4){0.f, 0.f, 0.f, 0.f};

    for (int kt = 0; kt < DM / BK; ++kt) {
        __syncthreads();
#pragma unroll
        for (int i = 0; i < PW; ++i) {
            const int rbase = (w * PW + i) * 16;
            const ushort* g;
            if (rbase < BM)
                g = Agl + (size_t)(m0 + rbase + lrow) * DM + kt * BK + lseg;
            else
                g = Bgl + (size_t)(n0 + rbase - BM + lrow) * DM + kt * BK + lseg;
            async_ld16(g, &S[rbase * BK]);
        }
        __syncthreads();

        bf16x8 af[MT], bfr[4];
#pragma unroll
        for (int mt = 0; mt < MT; ++mt)
            af[mt] = *(const bf16x8*)&S[(wm * WM + mt * 16 + l16) * BK + quad * 8];
#pragma unroll
        for (int nt = 0; nt < 4; ++nt)
            bfr[nt] = *(const bf16x8*)&S[(BM + wn * 64 + nt * 16 + l16) * BK + quad * 8];
#pragma unroll
        for (int mt = 0; mt < MT; ++mt)
#pragma unroll
            for (int nt = 0; nt < 4; ++nt)
                acc[mt][nt] = __builtin_amdgcn_mfma_f32_16x16x32_bf16(
                    af[mt], bfr[nt], acc[mt][nt], 0, 0, 0);
    }

    if (MODE == 1) {
#pragma unroll
        for (int mt = 0; mt < MT; ++mt)
#pragma unroll
            for (int r = 0; r < 4; ++r) {
                const int m = m0 + wm * WM + mt * 16 + quad * 4 + r;
#pragma unroll
                for (int nt = 0; nt < 4; ++nt) {
                    const int n = n0 + wn * 64 + nt * 16 + l16;
                    Fout[(size_t)m * DM + n] = acc[mt][nt][r];
                }
            }
    } else if (MODE == 0) {
        const int matb = n0 >> 10;                       // 0 = Q, 1 = K
        ushort* img = matb ? O1 : O0;
        const int hh = ((n0 & 1023) + wn * 64) >> 6;
        int dloc[4];
#pragma unroll
        for (int nt = 0; nt < 4; ++nt) dloc[nt] = nt * 16 + l16;
#pragma unroll
        for (int mt = 0; mt < MT; ++mt)
#pragma unroll
            for (int r = 0; r < 4; ++r) {
                const int m = m0 + wm * WM + mt * 16 + quad * 4 + r;
                const int bb = m >> 11;
                const int s = m & 2047;
                const size_t base =
                    ((size_t)(bb * NH + hh) * 32 + (s >> 6)) * 4096 + (s & 63) * 64;
                const int swz = s & 7;
#pragma unroll
                for (int nt = 0; nt < 4; ++nt) {
                    const float v = acc[mt][nt][r];
                    const float vp = __shfl_xor(v, 1);
                    const float2 cs = rtab[s * 32 + (dloc[nt] >> 1)];
                    float res = (dloc[nt] & 1) ? (vp * cs.y + v * cs.x)
                                               : (v * cs.x - vp * cs.y);
                    if (matb == 0) res *= CSC;           // fold softmax scale into Q
                    const int d = dloc[nt];
                    img[base + (((d >> 3) ^ swz) << 3) + (d & 7)] = f2bf(res);
                }
            }
    } else {
        // MODE 2: m index = d_global, n index = token
#pragma unroll
        for (int mt = 0; mt < MT; ++mt)
#pragma unroll
            for (int r = 0; r < 4; ++r) {
                const int dg = m0 + wm * WM + mt * 16 + quad * 4 + r;
                const int hh = dg >> 6, dd = dg & 63;
                const int swzd = dd & 7;
#pragma unroll
                for (int nt = 0; nt < 4; ++nt) {
                    const int token = n0 + wn * 64 + nt * 16 + l16;
                    const int bb = token >> 11;
                    const int s = token & 2047;
                    const size_t off =
                        ((size_t)(bb * NH + hh) * 32 + (s >> 6)) * 4096 + dd * 64 +
                        ((((s & 63) >> 3) ^ swzd) << 3) + (s & 7);
                    O0[off] = f2bf(acc[mt][nt][r]);
                }
            }
    }
}

// =====================================================================
// Flash attention v3: Q-tile 128/block (512 blocks, 2/CU, all resident),
// S^T formulation (A=K, B=Q) -> per-lane softmax state (q = l16),
// in-lane max/sum + 2 shuffles, P written as 4x ds_write_b64,
// double-buffered K/V via single-barrier async prefetch.
// Each wave owns q-rows {w*16..+15} and {64+w*16..+15} (2 frags).
// =====================================================================
__global__ __launch_bounds__(256, 2) void attn_mfma(
    const ushort* __restrict__ Qimg, const ushort* __restrict__ Kimg,
    const ushort* __restrict__ Vimg, ushort* __restrict__ Ob)
{
    const int t    = threadIdx.x;
    const int lane = t & 63;
    const int w    = t >> 6;
    const int l16  = lane & 15;
    const int quad = lane >> 4;
    const int swz  = l16 & 7;

    const int id = blockIdx.x;       // 0..511
    const int h  = id & 15;
    const int z  = id >> 4;          // 0..31
    const int b  = z & 1;
    const int qt = z >> 1;           // 0..15, 128-row q-tile

    const size_t bh = ((size_t)(b * NH + h)) * 32;
    const ushort* Qt = Qimg + (bh + (size_t)qt * 2) * 4096;   // 2 tiles, 16 KB
    const ushort* Kh = Kimg + bh * 4096;
    const ushort* Vh = Vimg + bh * 4096;

    __shared__ __align__(16) ushort Qs[8192];      // 128 q-rows
    __shared__ __align__(16) ushort Ks[2][4096];
    __shared__ __align__(16) ushort Vs[2][4096];
    __shared__ __align__(16) ushort Ps[8192];      // 128 q-rows x 64 keys

    // stage Q (flat 16 KB) + K/V tile 0
#pragma unroll
    for (int i = 0; i < 4; ++i)
        async_ld16(Qt + i * 2048 + w * 512 + lane * 8, &Qs[i * 2048 + w * 512]);
#pragma unroll
    for (int i = 0; i < 2; ++i) {
        async_ld16(Kh + i * 2048 + w * 512 + lane * 8, &Ks[0][i * 2048 + w * 512]);
        async_ld16(Vh + i * 2048 + w * 512 + lane * 8, &Vs[0][i * 2048 + w * 512]);
    }

    f32x4 Oacc[2][4];
    float m_i[2], l_i[2];
#pragma unroll
    for (int qf = 0; qf < 2; ++qf) {
        m_i[qf] = -1e30f; l_i[qf] = 0.f;
#pragma unroll
        for (int dblk = 0; dblk < 4; ++dblk) Oacc[qf][dblk] = (f32x4){0.f, 0.f, 0.f, 0.f};
    }

    const int ktmax = 2 * qt + 1;

    for (int kt = 0; kt <= ktmax; ++kt) {
        const int cur = kt & 1;
        __syncthreads();   // drains tile-kt async loads; guards buffer reuse

        if (kt < ktmax) {
            const int nb = cur ^ 1;
            const ushort* Kt = Kh + (size_t)(kt + 1) * 4096;
            const ushort* Vt = Vh + (size_t)(kt + 1) * 4096;
#pragma unroll
            for (int i = 0; i < 2; ++i) {
                async_ld16(Kt + i * 2048 + w * 512 + lane * 8, &Ks[nb][i * 2048 + w * 512]);
                async_ld16(Vt + i * 2048 + w * 512 + lane * 8, &Vs[nb][i * 2048 + w * 512]);
            }
        }

        // ---- K fragments (shared across both q-frags) ----
        bf16x8 aK[4][2];
#pragma unroll
        for (int ki = 0; ki < 4; ++ki)
#pragma unroll
            for (int ds = 0; ds < 2; ++ds)
                aK[ki][ds] = *(const bf16x8*)
                    &Ks[cur][(ki * 16 + l16) * 64 + (((ds * 4 + quad) ^ swz) << 3)];

        bool active[2];
#pragma unroll
        for (int qf = 0; qf < 2; ++qf) {
            const int qbase = qt * 128 + qf * 64 + w * 16;   // frag rows qbase..+15
            active[qf] = (kt * 64 <= qbase + 15);
            if (!active[qf]) continue;
            const bool need_mask = (kt * 64 + 63 > qbase);

            // ---- S^T = K Q^T : C[m=key][n=q], per-lane q = l16 ----
            const int qrow = qf * 64 + w * 16 + l16;
            bf16x8 bQ0 = *(const bf16x8*)&Qs[qrow * 64 + ((quad ^ swz) << 3)];
            bf16x8 bQ1 = *(const bf16x8*)&Qs[qrow * 64 + (((4 + quad) ^ swz) << 3)];
            f32x4 Sc[4];
#pragma unroll
            for (int ki = 0; ki < 4; ++ki) {
                Sc[ki] = (f32x4){0.f, 0.f, 0.f, 0.f};
                Sc[ki] = __builtin_amdgcn_mfma_f32_16x16x32_bf16(aK[ki][0], bQ0, Sc[ki], 0, 0, 0);
                Sc[ki] = __builtin_amdgcn_mfma_f32_16x16x32_bf16(aK[ki][1], bQ1, Sc[ki], 0, 0, 0);
            }

            // ---- softmax in S^T layout: lane owns q = qbase + l16 ----
            float ts[4][4];
            float mloc = -1e30f;
            if (need_mask) {
                const int qa = qbase + l16;
                const int ka = kt * 64 + quad * 4;
#pragma unroll
                for (int ki = 0; ki < 4; ++ki)
#pragma unroll
                    for (int r = 0; r < 4; ++r) {
                        float v = Sc[ki][r];
                        if (ka + ki * 16 + r > qa) v = -1e30f;
                        ts[ki][r] = v;
                        mloc = fmaxf(mloc, v);
                    }
            } else {
#pragma unroll
                for (int ki = 0; ki < 4; ++ki)
#pragma unroll
                    for (int r = 0; r < 4; ++r) {
                        ts[ki][r] = Sc[ki][r];
                        mloc = fmaxf(mloc, Sc[ki][r]);
                    }
            }
            mloc = fmaxf(mloc, __shfl_xor(mloc, 16));
            mloc = fmaxf(mloc, __shfl_xor(mloc, 32));
            const float mnew = fmaxf(m_i[qf], mloc);
            const float alpha = __builtin_amdgcn_exp2f(m_i[qf] - mnew);
            m_i[qf] = mnew;

            float psum = 0.f;
            const int prow = qrow * 64;
            const int pseg_half = (quad & 1) * 4;
#pragma unroll
            for (int ki = 0; ki < 4; ++ki) {
                float p0 = __builtin_amdgcn_exp2f(ts[ki][0] - mnew);
                float p1 = __builtin_amdgcn_exp2f(ts[ki][1] - mnew);
                float p2 = __builtin_amdgcn_exp2f(ts[ki][2] - mnew);
                float p3 = __builtin_amdgcn_exp2f(ts[ki][3] - mnew);
                psum += (p0 + p1) + (p2 + p3);
                ushort4 pk = { f2bf(p0), f2bf(p1), f2bf(p2), f2bf(p3) };
                const int seg = ki * 2 + (quad >> 1);
                *(ushort4*)&Ps[prow + (((seg ^ swz) << 3) + pseg_half)] = pk;
            }
            psum += __shfl_xor(psum, 16);
            psum += __shfl_xor(psum, 32);
            l_i[qf] = l_i[qf] * alpha + psum;

            // redistribute alpha (per-lane q=l16) to PV C-layout rows (q=quad*4+r)
#pragma unroll
            for (int r = 0; r < 4; ++r) {
                const float ar = __shfl(alpha, (lane & 48) | (quad * 4 + r));
#pragma unroll
                for (int dblk = 0; dblk < 4; ++dblk) Oacc[qf][dblk][r] *= ar;
            }
        }

        // ---- V fragments (shared across q-frags) ----
        bf16x8 bV[2][4];
#pragma unroll
        for (int ks = 0; ks < 2; ++ks)
#pragma unroll
            for (int dblk = 0; dblk < 4; ++dblk)
                bV[ks][dblk] = *(const bf16x8*)
                    &Vs[cur][(dblk * 16 + l16) * 64 + (((ks * 4 + quad) ^ swz) << 3)];

        // ---- O += P V (A = P rows, wave-private; no barrier) ----
#pragma unroll
        for (int qf = 0; qf < 2; ++qf) {
            if (!active[qf]) continue;
            const int qrow = qf * 64 + w * 16 + l16;
#pragma unroll
            for (int ks = 0; ks < 2; ++ks) {
                bf16x8 aP = *(const bf16x8*)
                    &Ps[qrow * 64 + (((ks * 4 + quad) ^ swz) << 3)];
#pragma unroll
                for (int dblk = 0; dblk < 4; ++dblk)
                    Oacc[qf][dblk] = __builtin_amdgcn_mfma_f32_16x16x32_bf16(
                        aP, bV[ks][dblk], Oacc[qf][dblk], 0, 0, 0);
            }
        }
    }

    // ---- epilogue: redistribute l, normalize, store bf16 (b, s, h*64+d) ----
#pragma unroll
    for (int qf = 0; qf < 2; ++qf)
#pragma unroll
        for (int r = 0; r < 4; ++r) {
            const float lr = __shfl(l_i[qf], (lane & 48) | (quad * 4 + r));
            const float inv = 1.0f / lr;
            const int q_abs = qt * 128 + qf * 64 + w * 16 + quad * 4 + r;
            ushort* dst = Ob + (size_t)(b * SEQ + q_abs) * DM + h * DK + l16;
#pragma unroll
            for (int dblk = 0; dblk < 4; ++dblk)
                dst[dblk * 16] = f2bf(Oacc[qf][dblk][r] * inv);
        }
}

// =====================================================================
extern "C" void kernel_launch(void* const* d_in, const int* in_sizes, int n_in,
                              void* d_out, int out_size, void* d_ws, size_t ws_size,
                              hipStream_t stream)
{
    const float* x  = (const float*)d_in[0];
    const float* Wq = (const float*)d_in[1];
    const float* Wk = (const float*)d_in[2];
    const float* Wv = (const float*)d_in[3];
    const float* Wo = (const float*)d_in[4];
    const int* pos  = (const int*)d_in[5];
    float* out = (float*)d_out;

    ushort* Xb    = (ushort*)d_ws;                    // 4096x1024
    ushort* Wqkb  = Xb + (size_t)MTOT * DM;           // 2048x1024 (Wq|Wk)
    ushort* Wvb   = Wqkb + (size_t)2 * DM * DM;       // 1024x1024
    ushort* Wob   = Wvb + (size_t)DM * DM;            // 1024x1024
    float2* rtab  = (float2*)(Wob + (size_t)DM * DM); // 2048*32 float2
    ushort* Qimg  = (ushort*)(rtab + SEQ * 32);
    ushort* Kimg  = Qimg + (size_t)MTOT * DM;
    ushort* Vimg  = Kimg + (size_t)MTOT * DM;
    ushort* attnb = Vimg + (size_t)MTOT * DM;

    dim3 blk(256);
    convert_kernel<<<dim3(1024, 6), blk, 0, stream>>>(
        x, Wq, Wk, Wv, Wo, pos, Xb, Wqkb, Wvb, Wob, rtab);
    // QK: M=4096 tokens, N=2048 (Wq|Wk)
    gemm_mfma<0><<<dim3(16, 32), blk, 0, stream>>>(
        Xb, Wqkb, rtab, Qimg, Kimg, nullptr);
    // V^T: M=1024 d-rows (A=Wv), N=4096 tokens (B=X)
    gemm_mfma<2><<<dim3(32, 16), blk, 0, stream>>>(
        Wvb, Xb, nullptr, Vimg, nullptr, nullptr);
    attn_mfma<<<dim3(512), blk, 0, stream>>>(Qimg, Kimg, Vimg, attnb);
    // OUT: M=4096, N=1024, fp32
    gemm_mfma<1><<<dim3(8, 64), blk, 0, stream>>>(
        attnb, Wob, nullptr, nullptr, nullptr, out);
}

// Round 7
// 187.520 us; speedup vs baseline: 8.4729x; 1.1421x over previous
//
#include <hip/hip_runtime.h>
#include <math.h>

#define SEQ  2048
#define DM   1024
#define NH   16
#define DK   64
#define MTOT 4096   // BATCH * SEQ
#define BATCH 2

typedef __attribute__((ext_vector_type(8))) short bf16x8;
typedef __attribute__((ext_vector_type(4))) float f32x4;

#define CSC 0.18033688011112042f   // 0.125 * log2(e), folded into Q image

__device__ __forceinline__ ushort f2bf(float f) {
    unsigned u = __builtin_bit_cast(unsigned, f);
    u += 0x7FFFu + ((u >> 16) & 1u);   // RNE
    return (ushort)(u >> 16);
}

__device__ __forceinline__ void async_ld16(const void* g, void* l) {
    __builtin_amdgcn_global_load_lds(
        (const __attribute__((address_space(1))) void*)g,
        (__attribute__((address_space(3))) void*)l, 16, 0, 0);
}

// Image layouts (per b,h: 32 tiles x 4096 ushort, one 64x64 tile each):
//   Q/K image: (tile, row=token_local, d):
//     off = tile*4096 + row*64 + (((d>>3) ^ (row&7))<<3) + (d&7)
//   V image (transposed): (tile, row=d, key_local k):
//     off = tile*4096 + d*64 + (((k>>3) ^ (d&7))<<3) + (k&7)
// XOR swizzle => all attention LDS b128 frag reads conflict-free with FLAT
// global_load_lds staging (verified R4: SQ_LDS_BANK_CONFLICT == 0).
// Q image values pre-scaled by CSC.

// =====================================================================
// convert: fp32 -> bf16 for X, Wq|Wk|Wv (concat), Wo; plus RoPE table
// =====================================================================
__global__ __launch_bounds__(256) void convert_kernel(
    const float* __restrict__ X, const float* __restrict__ Wq,
    const float* __restrict__ Wk, const float* __restrict__ Wv,
    const float* __restrict__ Wo, const int* __restrict__ pos,
    ushort* __restrict__ Xb, ushort* __restrict__ Wqkvb,
    ushort* __restrict__ Wob, float2* __restrict__ rtab)
{
    const int y = blockIdx.y;
    if (y == 5) {
        int i = blockIdx.x * 256 + threadIdx.x;
        if (i < SEQ * 32) {
            int s = i >> 5, j = i & 31;
            float freq = exp2f(-(float)(2 * j) * (13.287712379549449f / 64.0f));
            float ang = (float)pos[s] * freq;
            float sn, cs;
            sincosf(ang, &sn, &cs);
            rtab[i] = make_float2(cs, sn);
        }
        return;
    }
    const float* src; ushort* dst; int n;
    if (y == 0)      { src = X;  dst = Xb;                 n = MTOT * DM; }
    else if (y == 1) { src = Wq; dst = Wqkvb;              n = DM * DM; }
    else if (y == 2) { src = Wk; dst = Wqkvb + DM * DM;    n = DM * DM; }
    else if (y == 3) { src = Wv; dst = Wqkvb + 2 * DM * DM; n = DM * DM; }
    else             { src = Wo; dst = Wob;                n = DM * DM; }
    for (int i = (blockIdx.x * 256 + threadIdx.x) * 4; i < n; i += gridDim.x * 256 * 4) {
        float4 v = *(const float4*)(src + i);
        ushort4 o = { f2bf(v.x), f2bf(v.y), f2bf(v.z), f2bf(v.w) };
        *(ushort4*)(dst + i) = o;
    }
}

// =====================================================================
// bf16 MFMA GEMM: C[m][n] = sum_k A[m][k] * B[n][k], K = 1024.
// MODE 0 (QKV): BM=128,BN=128, N=3072 over Wq|Wk|Wv.
//   matb 0: RoPE + CSC -> Q image; matb 1: RoPE -> K image;
//   matb 2: transpose-scatter -> V image.
// MODE 1 (OUT): BM=64,BN=128. fp32 row-major store.
// =====================================================================
template <int MODE>
__global__ __launch_bounds__(256, 3) void gemm_mfma(
    const ushort* __restrict__ Agl, const ushort* __restrict__ Bgl,
    const float2* __restrict__ rtab, ushort* __restrict__ O0,
    ushort* __restrict__ O1, ushort* __restrict__ O2,
    float* __restrict__ Fout)
{
    constexpr int BM = (MODE == 0) ? 128 : 64;
    constexpr int BN = 128;
    constexpr int BK = 32;
    constexpr int WM = (MODE == 0) ? 64 : 32;
    constexpr int MT = WM / 16;
    constexpr int NINST = (BM + BN) / 16;
    constexpr int PW = NINST / 4;

    __shared__ __align__(16) ushort S[(BM + BN) * BK];

    const int t    = threadIdx.x;
    const int lane = t & 63;
    const int w    = t >> 6;
    const int wm   = w >> 1, wn = w & 1;
    const int l16  = lane & 15, quad = lane >> 4;
    const int lrow = lane >> 2;
    const int lseg = (lane & 3) * 8;

    const int bn = blockIdx.x, bm = blockIdx.y;
    const int m0 = bm * BM, n0 = bn * BN;

    f32x4 acc[MT][4];
#pragma unroll
    for (int mt = 0; mt < MT; ++mt)
#pragma unroll
        for (int nt = 0; nt < 4; ++nt) acc[mt][nt] = (f32x4){0.f, 0.f, 0.f, 0.f};

    for (int kt = 0; kt < DM / BK; ++kt) {
        __syncthreads();
#pragma unroll
        for (int i = 0; i < PW; ++i) {
            const int rbase = (w * PW + i) * 16;
            const ushort* g;
            if (rbase < BM)
                g = Agl + (size_t)(m0 + rbase + lrow) * DM + kt * BK + lseg;
            else
                g = Bgl + (size_t)(n0 + rbase - BM + lrow) * DM + kt * BK + lseg;
            async_ld16(g, &S[rbase * BK]);
        }
        __syncthreads();

        bf16x8 af[MT], bfr[4];
#pragma unroll
        for (int mt = 0; mt < MT; ++mt)
            af[mt] = *(const bf16x8*)&S[(wm * WM + mt * 16 + l16) * BK + quad * 8];
#pragma unroll
        for (int nt = 0; nt < 4; ++nt)
            bfr[nt] = *(const bf16x8*)&S[(BM + wn * 64 + nt * 16 + l16) * BK + quad * 8];
#pragma unroll
        for (int mt = 0; mt < MT; ++mt)
#pragma unroll
            for (int nt = 0; nt < 4; ++nt)
                acc[mt][nt] = __builtin_amdgcn_mfma_f32_16x16x32_bf16(
                    af[mt], bfr[nt], acc[mt][nt], 0, 0, 0);
    }

    if (MODE == 1) {
#pragma unroll
        for (int mt = 0; mt < MT; ++mt)
#pragma unroll
            for (int r = 0; r < 4; ++r) {
                const int m = m0 + wm * WM + mt * 16 + quad * 4 + r;
#pragma unroll
                for (int nt = 0; nt < 4; ++nt) {
                    const int n = n0 + wn * 64 + nt * 16 + l16;
                    Fout[(size_t)m * DM + n] = acc[mt][nt][r];
                }
            }
    } else {
        const int matb = n0 >> 10;                 // 0=Q, 1=K, 2=V
        if (matb < 2) {
            ushort* img = matb ? O1 : O0;
            const int hh = ((n0 & 1023) + wn * 64) >> 6;
            int dloc[4];
#pragma unroll
            for (int nt = 0; nt < 4; ++nt) dloc[nt] = nt * 16 + l16;
#pragma unroll
            for (int mt = 0; mt < MT; ++mt)
#pragma unroll
                for (int r = 0; r < 4; ++r) {
                    const int m = m0 + wm * WM + mt * 16 + quad * 4 + r;
                    const int bb = m >> 11;
                    const int s = m & 2047;
                    const size_t base =
                        ((size_t)(bb * NH + hh) * 32 + (s >> 6)) * 4096 + (s & 63) * 64;
                    const int swz = s & 7;
#pragma unroll
                    for (int nt = 0; nt < 4; ++nt) {
                        const float v = acc[mt][nt][r];
                        const float vp = __shfl_xor(v, 1);
                        const float2 cs = rtab[s * 32 + (dloc[nt] >> 1)];
                        float res = (dloc[nt] & 1) ? (vp * cs.y + v * cs.x)
                                                   : (v * cs.x - vp * cs.y);
                        if (matb == 0) res *= CSC;
                        const int d = dloc[nt];
                        img[base + (((d >> 3) ^ swz) << 3) + (d & 7)] = f2bf(res);
                    }
                }
        } else {
            // V: C[m=token][n=d_global] -> transposed V image
#pragma unroll
            for (int mt = 0; mt < MT; ++mt)
#pragma unroll
                for (int r = 0; r < 4; ++r) {
                    const int m = m0 + wm * WM + mt * 16 + quad * 4 + r;
                    const int bb = m >> 11;
                    const int s = m & 2047;
#pragma unroll
                    for (int nt = 0; nt < 4; ++nt) {
                        const int dgl = (n0 & 1023) + wn * 64 + nt * 16 + l16;
                        const int hh = dgl >> 6, dd = dgl & 63;
                        const size_t off =
                            ((size_t)(bb * NH + hh) * 32 + (s >> 6)) * 4096 + dd * 64 +
                            ((((s & 63) >> 3) ^ (dd & 7)) << 3) + (s & 7);
                        O2[off] = f2bf(acc[mt][nt][r]);
                    }
                }
        }
    }
}

// =====================================================================
// Flash attention v4b: uniform-work blocks (pair {p, 31-p} => 33 iters
// for EVERY block), 512 blocks, 4 waves, wave owns 16 q rows.
// S^T formulation (per-lane softmax, q = l16), Q in registers (global
// fragment loads), alpha/l redistribution via __shfl (R5-proven; R6's
// LDS broadcast caused NaN), K/V double-buffered async prefetch.
// =====================================================================
__global__ __launch_bounds__(256, 2) void attn_mfma(
    const ushort* __restrict__ Qimg, const ushort* __restrict__ Kimg,
    const ushort* __restrict__ Vimg, ushort* __restrict__ Ob)
{
    const int t    = threadIdx.x;
    const int lane = t & 63;
    const int w    = t >> 6;
    const int l16  = lane & 15;
    const int quad = lane >> 4;
    const int swz  = l16 & 7;

    const int id = blockIdx.x;       // 0..511
    const int h  = id & 15;
    const int z  = id >> 4;          // 0..31
    const int b  = z & 1;
    const int p  = z >> 1;           // 0..15
    const int qtB = 31 - p;          // phase A: qt=p (p+1 iters); B: 32-p iters

    const size_t bh = ((size_t)(b * NH + h)) * 32;
    const ushort* Kh = Kimg + bh * 4096;
    const ushort* Vh = Vimg + bh * 4096;

    __shared__ __align__(16) ushort Ks[2][4096];
    __shared__ __align__(16) ushort Vs[2][4096];
    __shared__ __align__(16) ushort Ps[4096];     // 64 q-rows x 64 keys

#define STAGE_KV(tile, buf)                                                  \
    do {                                                                     \
        const ushort* Kt_ = Kh + (size_t)(tile) * 4096;                      \
        const ushort* Vt_ = Vh + (size_t)(tile) * 4096;                      \
        _Pragma("unroll") for (int i_ = 0; i_ < 2; ++i_) {                   \
            async_ld16(Kt_ + i_ * 2048 + w * 512 + lane * 8,                 \
                       &Ks[buf][i_ * 2048 + w * 512]);                       \
            async_ld16(Vt_ + i_ * 2048 + w * 512 + lane * 8,                 \
                       &Vs[buf][i_ * 2048 + w * 512]);                       \
        }                                                                    \
    } while (0)

    const int qr = w * 16 + l16;   // wave-local q row (16 per wave)

    // Q fragments for phase A (direct global 16B loads; swizzle in image)
    bf16x8 bQ0, bQ1;
    {
        const ushort* Qt = Qimg + (bh + p) * 4096;
        bQ0 = *(const bf16x8*)(Qt + qr * 64 + ((quad ^ swz) << 3));
        bQ1 = *(const bf16x8*)(Qt + qr * 64 + (((4 + quad) ^ swz) << 3));
    }

    STAGE_KV(0, 0);

    f32x4 Oacc[4];
    float m_i = -1e30f, l_i = 0.f;
#pragma unroll
    for (int d = 0; d < 4; ++d) Oacc[d] = (f32x4){0.f, 0.f, 0.f, 0.f};

    int qt = p;

    auto writeO = [&](int qtw) {
#pragma unroll
        for (int r = 0; r < 4; ++r) {
            const float lr = __shfl(l_i, (lane & 48) | (quad * 4 + r));
            const float inv = 1.0f / lr;
            const int q_abs = qtw * 64 + w * 16 + quad * 4 + r;
            ushort* dst = Ob + (size_t)(b * SEQ + q_abs) * DM + h * DK + l16;
#pragma unroll
            for (int dblk = 0; dblk < 4; ++dblk)
                dst[dblk * 16] = f2bf(Oacc[dblk][r] * inv);
        }
    };

    for (int it = 0; it <= 32; ++it) {
        const int cur = it & 1;
        const int kt = (it <= p) ? it : it - (p + 1);
        __syncthreads();   // drains this tile's async loads; guards buffers

        if (it < 32) {
            const int itn = it + 1;
            const int ktn = (itn <= p) ? itn : itn - (p + 1);
            STAGE_KV(ktn, cur ^ 1);
        }

        // ---- fragments from LDS (K for S^T; V for PV, independent) ----
        bf16x8 aK[4][2];
#pragma unroll
        for (int ki = 0; ki < 4; ++ki)
#pragma unroll
            for (int ds = 0; ds < 2; ++ds)
                aK[ki][ds] = *(const bf16x8*)
                    &Ks[cur][(ki * 16 + l16) * 64 + (((ds * 4 + quad) ^ swz) << 3)];
        bf16x8 bV[2][4];
#pragma unroll
        for (int s2 = 0; s2 < 2; ++s2)
#pragma unroll
            for (int dblk = 0; dblk < 4; ++dblk)
                bV[s2][dblk] = *(const bf16x8*)
                    &Vs[cur][(dblk * 16 + l16) * 64 + (((s2 * 4 + quad) ^ swz) << 3)];

        // ---- S^T = K Q^T : per-lane q = l16 ----
        f32x4 Sc[4];
#pragma unroll
        for (int ki = 0; ki < 4; ++ki) {
            Sc[ki] = (f32x4){0.f, 0.f, 0.f, 0.f};
            Sc[ki] = __builtin_amdgcn_mfma_f32_16x16x32_bf16(aK[ki][0], bQ0, Sc[ki], 0, 0, 0);
            Sc[ki] = __builtin_amdgcn_mfma_f32_16x16x32_bf16(aK[ki][1], bQ1, Sc[ki], 0, 0, 0);
        }

        // ---- softmax (per-lane over 16 vals, then 2 cross-quad shuffles) ----
        float ts[4][4];
        float mloc = -1e30f;
        if (kt == qt) {   // diagonal tile: causal mask (tile-local indices)
            const int qa = w * 16 + l16;
            const int ka = quad * 4;
#pragma unroll
            for (int ki = 0; ki < 4; ++ki)
#pragma unroll
                for (int r = 0; r < 4; ++r) {
                    float v = Sc[ki][r];
                    if (ka + ki * 16 + r > qa) v = -1e30f;
                    ts[ki][r] = v;
                    mloc = fmaxf(mloc, v);
                }
        } else {
#pragma unroll
            for (int ki = 0; ki < 4; ++ki)
#pragma unroll
                for (int r = 0; r < 4; ++r) {
                    ts[ki][r] = Sc[ki][r];
                    mloc = fmaxf(mloc, Sc[ki][r]);
                }
        }
        mloc = fmaxf(mloc, __shfl_xor(mloc, 16));
        mloc = fmaxf(mloc, __shfl_xor(mloc, 32));
        const float mnew = fmaxf(m_i, mloc);
        const float alpha = __builtin_amdgcn_exp2f(m_i - mnew);
        m_i = mnew;

        float psum = 0.f;
        const int prow = qr * 64;
        const int phalf = (quad & 1) * 4;
#pragma unroll
        for (int ki = 0; ki < 4; ++ki) {
            float p0 = __builtin_amdgcn_exp2f(ts[ki][0] - mnew);
            float p1 = __builtin_amdgcn_exp2f(ts[ki][1] - mnew);
            float p2 = __builtin_amdgcn_exp2f(ts[ki][2] - mnew);
            float p3 = __builtin_amdgcn_exp2f(ts[ki][3] - mnew);
            psum += (p0 + p1) + (p2 + p3);
            ushort4 pk = { f2bf(p0), f2bf(p1), f2bf(p2), f2bf(p3) };
            const int seg = ki * 2 + (quad >> 1);
            *(ushort4*)&Ps[prow + (((seg ^ swz) << 3) + phalf)] = pk;
        }
        psum += __shfl_xor(psum, 16);
        psum += __shfl_xor(psum, 32);
        l_i = l_i * alpha + psum;

        // alpha redistribution: lane-q (l16) -> C-layout rows (quad*4+r)
        // (alpha is uniform across quads for fixed l16; R5-proven shfl)
        float ar[4];
#pragma unroll
        for (int r = 0; r < 4; ++r)
            ar[r] = __shfl(alpha, (lane & 48) | (quad * 4 + r));
#pragma unroll
        for (int dblk = 0; dblk < 4; ++dblk)
#pragma unroll
            for (int r = 0; r < 4; ++r) Oacc[dblk][r] *= ar[r];

        // ---- O += P V (Ps rows wave-private; no barrier) ----
#pragma unroll
        for (int s2 = 0; s2 < 2; ++s2) {
            bf16x8 aP = *(const bf16x8*)&Ps[prow + (((s2 * 4 + quad) ^ swz) << 3)];
#pragma unroll
            for (int dblk = 0; dblk < 4; ++dblk)
                Oacc[dblk] = __builtin_amdgcn_mfma_f32_16x16x32_bf16(
                    aP, bV[s2][dblk], Oacc[dblk], 0, 0, 0);
        }

        // ---- phase switch: write phase-A output, reset for phase B ----
        if (it == p) {
            writeO(p);
            m_i = -1e30f; l_i = 0.f;
#pragma unroll
            for (int d = 0; d < 4; ++d) Oacc[d] = (f32x4){0.f, 0.f, 0.f, 0.f};
            qt = qtB;
            const ushort* Qt = Qimg + (bh + qtB) * 4096;
            bQ0 = *(const bf16x8*)(Qt + qr * 64 + ((quad ^ swz) << 3));
            bQ1 = *(const bf16x8*)(Qt + qr * 64 + (((4 + quad) ^ swz) << 3));
        }
    }

    writeO(qtB);
#undef STAGE_KV
}

// =====================================================================
extern "C" void kernel_launch(void* const* d_in, const int* in_sizes, int n_in,
                              void* d_out, int out_size, void* d_ws, size_t ws_size,
                              hipStream_t stream)
{
    const float* x  = (const float*)d_in[0];
    const float* Wq = (const float*)d_in[1];
    const float* Wk = (const float*)d_in[2];
    const float* Wv = (const float*)d_in[3];
    const float* Wo = (const float*)d_in[4];
    const int* pos  = (const int*)d_in[5];
    float* out = (float*)d_out;

    ushort* Xb    = (ushort*)d_ws;                     // 4096x1024
    ushort* Wqkvb = Xb + (size_t)MTOT * DM;            // 3072x1024
    ushort* Wob   = Wqkvb + (size_t)3 * DM * DM;       // 1024x1024
    float2* rtab  = (float2*)(Wob + (size_t)DM * DM);  // 2048*32
    ushort* Qimg  = (ushort*)(rtab + SEQ * 32);
    ushort* Kimg  = Qimg + (size_t)MTOT * DM;
    ushort* Vimg  = Kimg + (size_t)MTOT * DM;
    ushort* attnb = Vimg + (size_t)MTOT * DM;

    dim3 blk(256);
    convert_kernel<<<dim3(1024, 6), blk, 0, stream>>>(
        x, Wq, Wk, Wv, Wo, pos, Xb, Wqkvb, Wob, rtab);
    // QKV: M=4096 tokens, N=3072 (Wq|Wk|Wv) -> Q/K/V images
    gemm_mfma<0><<<dim3(24, 32), blk, 0, stream>>>(
        Xb, Wqkvb, rtab, Qimg, Kimg, Vimg, nullptr);
    attn_mfma<<<dim3(512), blk, 0, stream>>>(Qimg, Kimg, Vimg, attnb);
    // OUT: M=4096, N=1024, fp32
    gemm_mfma<1><<<dim3(8, 64), blk, 0, stream>>>(
        attnb, Wob, nullptr, nullptr, nullptr, nullptr, out);
}